// Round 3
// baseline (10139.873 us; speedup 1.0000x reference)
//
#include <hip/hip_runtime.h>
#include <math.h>

#define NWIN 13
#define DD 8

__device__ __forceinline__ float4 ld4(const float* p) {
    return *reinterpret_cast<const float4*>(p);
}
__device__ __forceinline__ void st4(float* p, float4 v) {
    *reinterpret_cast<float4*>(p) = v;
}
__device__ __forceinline__ void fma4(float4& a, float s, float4 w) {
    a.x = fmaf(s, w.x, a.x);
    a.y = fmaf(s, w.y, a.y);
    a.z = fmaf(s, w.z, a.z);
    a.w = fmaf(s, w.w, a.w);
}
__device__ __forceinline__ float sigmoidf(float x) { return 1.f / (1.f + expf(-x)); }

// ---------------------------------------------------------------------------
// First conv: CIN=3, window extraction fused. in = (20,56,56,3) for one batch.
// out = (13,8,56,56,32). grid = 13*8*56, block (64,4).
// ---------------------------------------------------------------------------
__global__ __launch_bounds__(256)
void conv_c11_k(const float* __restrict__ in, const float* __restrict__ wgt,
                const float* __restrict__ bias, float* __restrict__ out)
{
    constexpr int HH = 56, WW = 56, WP = 58, CINP = 4, COUT = 32;
    __shared__ float lds[3 * WP * CINP];
    const int blk = blockIdx.x;
    const int h = blk % HH;
    const int d = (blk / HH) % DD;
    const int n = blk / (HH * DD);          // window index = start frame t
    const int tx = threadIdx.x, ty = threadIdx.y;
    const int tid = ty * 64 + tx;

    for (int i = tid * 4; i < 3 * WP * CINP; i += 256 * 4)
        st4(&lds[i], float4{0.f, 0.f, 0.f, 0.f});

    const int c0 = ty * 8;
    float4 acc0 = {0, 0, 0, 0}, acc1 = {0, 0, 0, 0};

    for (int kd = 0; kd < 3; ++kd) {
        const int d2 = d + kd - 1;          // window-local depth (SAME padding)
        const bool dok = (d2 >= 0) && (d2 < DD);
        __syncthreads();
        if (dok) {
            const int frame = n + d2;       // global time index
            for (int i = tid; i < 3 * WW; i += 256) {
                int kh = i / WW, w = i - kh * WW;
                int h2 = h + kh - 1;
                if (h2 >= 0 && h2 < HH) {
                    const float* src = &in[((frame * HH + h2) * WW + w) * 3];
                    float* dst = &lds[(kh * WP + (w + 1)) * CINP];
                    dst[0] = src[0]; dst[1] = src[1]; dst[2] = src[2];
                }
            }
        }
        __syncthreads();
        if (dok && tx < WW) {
            #pragma unroll
            for (int kh = 0; kh < 3; ++kh) {
                #pragma unroll
                for (int kw = 0; kw < 3; ++kw) {
                    const float* lrow = &lds[(kh * WP + tx + kw) * CINP];
                    const float* wrow = &wgt[(((kd * 3 + kh) * 3 + kw) * 3) * COUT + c0];
                    #pragma unroll
                    for (int ci = 0; ci < 3; ++ci) {
                        float s = lrow[ci];
                        float4 wa = ld4(wrow + ci * COUT);
                        float4 wb = ld4(wrow + ci * COUT + 4);
                        fma4(acc0, s, wa);
                        fma4(acc1, s, wb);
                    }
                }
            }
        }
    }
    if (tx < WW) {
        float4 ba = ld4(bias + c0), bb = ld4(bias + c0 + 4);
        acc0.x = fmaxf(acc0.x + ba.x, 0.f); acc0.y = fmaxf(acc0.y + ba.y, 0.f);
        acc0.z = fmaxf(acc0.z + ba.z, 0.f); acc0.w = fmaxf(acc0.w + ba.w, 0.f);
        acc1.x = fmaxf(acc1.x + bb.x, 0.f); acc1.y = fmaxf(acc1.y + bb.y, 0.f);
        acc1.z = fmaxf(acc1.z + bb.z, 0.f); acc1.w = fmaxf(acc1.w + bb.w, 0.f);
        size_t ob = (((size_t)(n * DD + d) * HH + h) * WW + tx) * COUT + c0;
        st4(&out[ob], acc0);
        st4(&out[ob + 4], acc1);
    }
}

// ---------------------------------------------------------------------------
// Generic conv3d, SAME padding over (8,HH,WW), relu+bias fused.
// in/out: (13,8,HH,WW,CIN/COUT). grid = 13*8*HH, block (BX,BY), COUT == BY*8.
// LDS: per-kd slice of 3 kh-rows, CIN+4 pad -> conflict-free ds_read_b128.
// ---------------------------------------------------------------------------
template<int CIN, int COUT, int HH, int WW, int BX, int BY>
__global__ __launch_bounds__(BX * BY)
void conv3d_k(const float* __restrict__ in, const float* __restrict__ wgt,
              const float* __restrict__ bias, float* __restrict__ out)
{
    constexpr int CINP = CIN + 4;
    constexpr int WP = WW + 2;
    constexpr int NT = BX * BY;
    static_assert(COUT == BY * 8, "cout mapping");
    __shared__ float lds[3 * WP * CINP];

    const int blk = blockIdx.x;
    const int h = blk % HH;
    const int d = (blk / HH) % DD;
    const int n = blk / (HH * DD);
    const int tx = threadIdx.x, ty = threadIdx.y;
    const int tid = ty * BX + tx;

    for (int i = tid * 4; i < 3 * WP * CINP; i += NT * 4)
        st4(&lds[i], float4{0.f, 0.f, 0.f, 0.f});

    const int c0 = ty * 8;
    float4 acc0 = {0, 0, 0, 0}, acc1 = {0, 0, 0, 0};

    for (int kd = 0; kd < 3; ++kd) {
        const int d2 = d + kd - 1;
        const bool dok = (d2 >= 0) && (d2 < DD);
        __syncthreads();
        if (dok) {
            constexpr int ROWF4 = WW * (CIN / 4);
            for (int i = tid; i < 3 * ROWF4; i += NT) {
                int kh = i / ROWF4;
                int rem = i - kh * ROWF4;
                int w = rem / (CIN / 4);
                int ci = (rem - w * (CIN / 4)) * 4;
                int h2 = h + kh - 1;
                if (h2 >= 0 && h2 < HH) {
                    float4 v = ld4(&in[(((size_t)(n * DD + d2) * HH + h2) * WW + w) * CIN + ci]);
                    st4(&lds[(kh * WP + (w + 1)) * CINP + ci], v);
                }
            }
        }
        __syncthreads();
        if (dok && tx < WW) {
            #pragma unroll
            for (int kh = 0; kh < 3; ++kh) {
                #pragma unroll
                for (int kw = 0; kw < 3; ++kw) {
                    const float* lrow = &lds[(kh * WP + tx + kw) * CINP];
                    const float* wrow = &wgt[(size_t)(((kd * 3 + kh) * 3 + kw) * CIN) * COUT + c0];
                    #pragma unroll 4
                    for (int ci = 0; ci < CIN; ci += 4) {
                        float4 iv = ld4(lrow + ci);
                        float4 wa, wb;
                        wa = ld4(wrow + (ci + 0) * COUT); wb = ld4(wrow + (ci + 0) * COUT + 4);
                        fma4(acc0, iv.x, wa); fma4(acc1, iv.x, wb);
                        wa = ld4(wrow + (ci + 1) * COUT); wb = ld4(wrow + (ci + 1) * COUT + 4);
                        fma4(acc0, iv.y, wa); fma4(acc1, iv.y, wb);
                        wa = ld4(wrow + (ci + 2) * COUT); wb = ld4(wrow + (ci + 2) * COUT + 4);
                        fma4(acc0, iv.z, wa); fma4(acc1, iv.z, wb);
                        wa = ld4(wrow + (ci + 3) * COUT); wb = ld4(wrow + (ci + 3) * COUT + 4);
                        fma4(acc0, iv.w, wa); fma4(acc1, iv.w, wb);
                    }
                }
            }
        }
    }
    if (tx < WW) {
        float4 ba = ld4(bias + c0), bb = ld4(bias + c0 + 4);
        acc0.x = fmaxf(acc0.x + ba.x, 0.f); acc0.y = fmaxf(acc0.y + ba.y, 0.f);
        acc0.z = fmaxf(acc0.z + ba.z, 0.f); acc0.w = fmaxf(acc0.w + ba.w, 0.f);
        acc1.x = fmaxf(acc1.x + bb.x, 0.f); acc1.y = fmaxf(acc1.y + bb.y, 0.f);
        acc1.z = fmaxf(acc1.z + bb.z, 0.f); acc1.w = fmaxf(acc1.w + bb.w, 0.f);
        size_t ob = (((size_t)(n * DD + d) * HH + h) * WW + tx) * COUT + c0;
        st4(&out[ob], acc0);
        st4(&out[ob + 4], acc1);
    }
}

// ---------------------------------------------------------------------------
// MaxPool (1,2,2) valid. in (13*8, 2*HO, 2*WO, C) -> out (13*8, HO, WO, C)
// ---------------------------------------------------------------------------
template<int C, int HO, int WO>
__global__ __launch_bounds__(256)
void pool_k(const float* __restrict__ in, float* __restrict__ out, int total4)
{
    constexpr int C4 = C / 4;
    for (int idx = blockIdx.x * 256 + threadIdx.x; idx < total4; idx += gridDim.x * 256) {
        int c4 = idx % C4;
        int t = idx / C4;
        int wo = t % WO; t /= WO;
        int ho = t % HO; t /= HO;            // t = n*8+d
        size_t base = (((size_t)t * (2 * HO) + 2 * ho) * (2 * WO) + 2 * wo) * C + c4 * 4;
        float4 a = ld4(&in[base]);
        float4 b = ld4(&in[base + C]);
        float4 c = ld4(&in[base + (size_t)(2 * WO) * C]);
        float4 e = ld4(&in[base + (size_t)(2 * WO) * C + C]);
        float4 m;
        m.x = fmaxf(fmaxf(a.x, b.x), fmaxf(c.x, e.x));
        m.y = fmaxf(fmaxf(a.y, b.y), fmaxf(c.y, e.y));
        m.z = fmaxf(fmaxf(a.z, b.z), fmaxf(c.z, e.z));
        m.w = fmaxf(fmaxf(a.w, b.w), fmaxf(c.w, e.w));
        st4(&out[(size_t)idx * 4], m);
    }
}

// ---------------------------------------------------------------------------
// GlobalAveragePooling3D: in (13,8,14,14,128) -> feats (13,128)
// grid 13, block (128,8)
// ---------------------------------------------------------------------------
__global__ __launch_bounds__(1024)
void gap_k(const float* __restrict__ in, float* __restrict__ outf)
{
    __shared__ float part[8][128];
    const int n = blockIdx.x;
    const int c = threadIdx.x;
    const int dy = threadIdx.y;
    float s = 0.f;
    const float* p = &in[((size_t)n * 1568 + dy * 196) * 128 + c];
    #pragma unroll 4
    for (int i = 0; i < 196; ++i) s += p[(size_t)i * 128];
    part[dy][c] = s;
    __syncthreads();
    if (dy == 0) {
        float t = 0.f;
        #pragma unroll
        for (int k = 0; k < 8; ++k) t += part[k][c];
        outf[n * 128 + c] = t * (1.f / 1568.f);
    }
}

// ---------------------------------------------------------------------------
// 3x GRU (Keras reset_after=true) + dense head + softmax. Single block of 384.
// feats: (2,13,128). out: throw (2,64) then tori (2,2) = 132 floats.
// ---------------------------------------------------------------------------
__global__ __launch_bounds__(384)
void gru_head_k(const float* __restrict__ feats,
                const float* __restrict__ g1_wx, const float* __restrict__ g1_wh, const float* __restrict__ g1_b,
                const float* __restrict__ g2_wx, const float* __restrict__ g2_wh, const float* __restrict__ g2_b,
                const float* __restrict__ g3_wx, const float* __restrict__ g3_wh, const float* __restrict__ g3_b,
                const float* __restrict__ d1_w, const float* __restrict__ d1_b,
                const float* __restrict__ d2_w, const float* __restrict__ d2_b,
                const float* __restrict__ thr_w, const float* __restrict__ thr_b,
                const float* __restrict__ tori_w, const float* __restrict__ tori_b,
                float* __restrict__ out)
{
    __shared__ float xs[26 * 128];
    __shared__ float xp[13 * 2 * 192];
    __shared__ float seq[26 * 64];
    __shared__ float rec[2 * 192];
    __shared__ float hbuf[2 * 64];
    __shared__ float tmp[2 * 64];
    __shared__ float hd2[2 * 32];
    __shared__ float red[4];
    __shared__ float tl[4];
    const int tid = threadIdx.x;

    for (int i = tid; i < 26 * 128; i += 384) xs[i] = feats[i];
    __syncthreads();

    const float* WXs[3] = {g1_wx, g2_wx, g3_wx};
    const float* WHs[3] = {g1_wh, g2_wh, g3_wh};
    const float* GBs[3] = {g1_b, g2_b, g3_b};

    for (int layer = 0; layer < 3; ++layer) {
        const int K = (layer == 0) ? 128 : 64;
        const float* wx = WXs[layer];
        const float* wh = WHs[layer];
        const float* gb = GBs[layer];
        // xp[t][b][j] = x[b][t] . wx[:,j] + gb[j]
        for (int i = tid; i < 13 * 2 * 192; i += 384) {
            int j = i % 192;
            int tb = i / 192;
            int b = tb % 2, t = tb / 2;
            const float* xrow = &xs[(b * 13 + t) * K];
            float s = gb[j];
            for (int k = 0; k < K; ++k) s = fmaf(xrow[k], wx[k * 192 + j], s);
            xp[(t * 2 + b) * 192 + j] = s;
        }
        if (tid < 128) hbuf[tid] = 0.f;
        __syncthreads();
        for (int t = 0; t < 13; ++t) {
            {
                int b = tid / 192, j = tid % 192;
                const float* hrow = &hbuf[b * 64];
                float s = gb[192 + j];
                #pragma unroll 4
                for (int k = 0; k < 64; ++k) s = fmaf(hrow[k], wh[k * 192 + j], s);
                rec[tid] = s;
            }
            __syncthreads();
            if (tid < 128) {
                int b = tid / 64, u = tid % 64;
                const float* xpt = &xp[(t * 2 + b) * 192];
                const float* rc = &rec[b * 192];
                float z = sigmoidf(xpt[u] + rc[u]);
                float r = sigmoidf(xpt[64 + u] + rc[64 + u]);
                float hh = tanhf(xpt[128 + u] + r * rc[128 + u]);
                float hn = z * hbuf[b * 64 + u] + (1.f - z) * hh;
                hbuf[b * 64 + u] = hn;
                seq[(b * 13 + t) * 64 + u] = hn;
            }
            __syncthreads();
        }
        if (layer < 2) {
            for (int i = tid; i < 26 * 64; i += 384) xs[i] = seq[i];
            __syncthreads();
        }
    }

    // d1: 64->64 relu
    if (tid < 128) {
        int b = tid / 64, u = tid % 64;
        float s = d1_b[u];
        for (int k = 0; k < 64; ++k) s = fmaf(hbuf[b * 64 + k], d1_w[k * 64 + u], s);
        tmp[b * 64 + u] = fmaxf(s, 0.f);
    }
    __syncthreads();
    // d2: 64->32 relu
    if (tid < 64) {
        int b = tid / 32, u = tid % 32;
        float s = d2_b[u];
        for (int k = 0; k < 64; ++k) s = fmaf(tmp[b * 64 + k], d2_w[k * 32 + u], s);
        hd2[b * 32 + u] = fmaxf(s, 0.f);
    }
    __syncthreads();
    // throw logits: 32->64
    if (tid < 128) {
        int b = tid / 64, u = tid % 64;
        float s = thr_b[u];
        for (int k = 0; k < 32; ++k) s = fmaf(hd2[b * 32 + k], thr_w[k * 64 + u], s);
        tmp[b * 64 + u] = s;
    }
    // tori logits: 32->2
    if (tid >= 128 && tid < 132) {
        int i = tid - 128;
        int b = i >> 1, u = i & 1;
        float s = tori_b[u];
        for (int k = 0; k < 32; ++k) s = fmaf(hd2[b * 32 + k], tori_w[k * 2 + u], s);
        tl[i] = s;
    }
    __syncthreads();
    if (tid < 2) {
        float m = -1e30f;
        for (int u = 0; u < 64; ++u) m = fmaxf(m, tmp[tid * 64 + u]);
        float s = 0.f;
        for (int u = 0; u < 64; ++u) s += expf(tmp[tid * 64 + u] - m);
        red[tid * 2] = m;
        red[tid * 2 + 1] = s;
    }
    __syncthreads();
    if (tid < 128) {
        int b = tid >> 6;
        out[tid] = expf(tmp[tid] - red[b * 2]) / red[b * 2 + 1];
    }
    if (tid >= 128 && tid < 130) {
        int b = tid - 128;
        float a = tl[b * 2], c = tl[b * 2 + 1];
        float m = fmaxf(a, c);
        float e0 = expf(a - m), e1 = expf(c - m);
        float inv = 1.f / (e0 + e1);
        out[128 + b * 2 + 0] = e0 * inv;
        out[128 + b * 2 + 1] = e1 * inv;
    }
}

// ---------------------------------------------------------------------------
extern "C" void kernel_launch(void* const* d_in, const int* in_sizes, int n_in,
                              void* d_out, int out_size, void* d_ws, size_t ws_size,
                              hipStream_t stream) {
    const float* inputs = (const float*)d_in[0];
    const float* c11_k = (const float*)d_in[1];  const float* c11_b = (const float*)d_in[2];
    const float* c12_k = (const float*)d_in[3];  const float* c12_b = (const float*)d_in[4];
    const float* c21_k = (const float*)d_in[5];  const float* c21_b = (const float*)d_in[6];
    const float* c22_k = (const float*)d_in[7];  const float* c22_b = (const float*)d_in[8];
    const float* c31_k = (const float*)d_in[9];  const float* c31_b = (const float*)d_in[10];
    const float* c32_k = (const float*)d_in[11]; const float* c32_b = (const float*)d_in[12];
    const float* g1_wx = (const float*)d_in[13]; const float* g1_wh = (const float*)d_in[14]; const float* g1_b = (const float*)d_in[15];
    const float* g2_wx = (const float*)d_in[16]; const float* g2_wh = (const float*)d_in[17]; const float* g2_b = (const float*)d_in[18];
    const float* g3_wx = (const float*)d_in[19]; const float* g3_wh = (const float*)d_in[20]; const float* g3_b = (const float*)d_in[21];
    const float* d1_w = (const float*)d_in[22];  const float* d1_b = (const float*)d_in[23];
    const float* d2_w = (const float*)d_in[24];  const float* d2_b = (const float*)d_in[25];
    const float* thr_w = (const float*)d_in[26]; const float* thr_b = (const float*)d_in[27];
    const float* tori_w = (const float*)d_in[28]; const float* tori_b = (const float*)d_in[29];

    float* ws = (float*)d_ws;
    const size_t BUF = (size_t)NWIN * 8 * 56 * 56 * 32;   // 10,436,608 floats
    float* buf0 = ws;
    float* buf1 = ws + BUF;
    float* feats = ws + 2 * BUF;                          // 26*128 floats
    float* out = (float*)d_out;

    for (int b = 0; b < 2; ++b) {
        const float* inb = inputs + (size_t)b * 20 * 56 * 56 * 3;
        conv_c11_k<<<NWIN * 8 * 56, dim3(64, 4), 0, stream>>>(inb, c11_k, c11_b, buf0);
        conv3d_k<32, 32, 56, 56, 64, 4><<<NWIN * 8 * 56, dim3(64, 4), 0, stream>>>(buf0, c12_k, c12_b, buf1);
        pool_k<32, 28, 28><<<1024, 256, 0, stream>>>(buf1, buf0, NWIN * 8 * 28 * 28 * 32 / 4);
        conv3d_k<32, 64, 28, 28, 32, 8><<<NWIN * 8 * 28, dim3(32, 8), 0, stream>>>(buf0, c21_k, c21_b, buf1);
        conv3d_k<64, 64, 28, 28, 32, 8><<<NWIN * 8 * 28, dim3(32, 8), 0, stream>>>(buf1, c22_k, c22_b, buf0);
        pool_k<64, 14, 14><<<1024, 256, 0, stream>>>(buf0, buf1, NWIN * 8 * 14 * 14 * 64 / 4);
        conv3d_k<64, 128, 14, 14, 16, 16><<<NWIN * 8 * 14, dim3(16, 16), 0, stream>>>(buf1, c31_k, c31_b, buf0);
        conv3d_k<128, 128, 14, 14, 16, 16><<<NWIN * 8 * 14, dim3(16, 16), 0, stream>>>(buf0, c32_k, c32_b, buf1);
        gap_k<<<NWIN, dim3(128, 8), 0, stream>>>(buf1, feats + b * NWIN * 128);
    }
    gru_head_k<<<1, 384, 0, stream>>>(feats,
        g1_wx, g1_wh, g1_b, g2_wx, g2_wh, g2_b, g3_wx, g3_wh, g3_b,
        d1_w, d1_b, d2_w, d2_b, thr_w, thr_b, tori_w, tori_b, out);
}

// Round 6
// 1322.705 us; speedup vs baseline: 7.6660x; 7.6660x over previous
//
#include <hip/hip_runtime.h>
#include <math.h>

#define DD 8

typedef __attribute__((ext_vector_type(8))) short short8v;
typedef __attribute__((ext_vector_type(4))) float f32x4;

__device__ __forceinline__ float4 ld4(const float* p) {
    return *reinterpret_cast<const float4*>(p);
}
__device__ __forceinline__ void st4(float* p, float4 v) {
    *reinterpret_cast<float4*>(p) = v;
}
__device__ __forceinline__ void fma4(float4& a, float s, float4 w) {
    a.x = fmaf(s, w.x, a.x);
    a.y = fmaf(s, w.y, a.y);
    a.z = fmaf(s, w.z, a.z);
    a.w = fmaf(s, w.w, a.w);
}
__device__ __forceinline__ float sigmoidf(float x) { return 1.f / (1.f + expf(-x)); }

__device__ __forceinline__ float bf2f(unsigned short u) {
    union { unsigned int i; float f; } v; v.i = ((unsigned int)u) << 16; return v.f;
}
__device__ __forceinline__ unsigned short f2bf(float f) {
    union { float f; unsigned int i; } v; v.f = f;
    unsigned int r = v.i + 0x7FFFu + ((v.i >> 16) & 1u);
    return (unsigned short)(r >> 16);
}

// ---------------------------------------------------------------------------
// Weight pre-pack: wgt (K=27*CIN, COUT) fp32 -> bf16 fragments.
// pk[((nt*chunks + chunk)*64 + lane)*8 + j] = wgt[k][cout],
//   k = chunk*32 + (lane>>4)*8 + j, cout = nt*16 + (lane&15).
// ---------------------------------------------------------------------------
__global__ __launch_bounds__(256)
void pack_w_k(const float* __restrict__ wgt, unsigned short* __restrict__ pk,
              int chunks, int cout_n, int total)
{
    for (int id = blockIdx.x * 256 + threadIdx.x; id < total; id += gridDim.x * 256) {
        int j = id & 7;
        int l = (id >> 3) & 63;
        int rest = id >> 9;
        int chunk = rest % chunks;
        int nt = rest / chunks;
        int k = chunk * 32 + ((l >> 4) << 3) + j;
        int cout = nt * 16 + (l & 15);
        pk[id] = f2bf(wgt[(size_t)k * cout_n + cout]);
    }
}

// ---------------------------------------------------------------------------
// First conv fp32 direct (CIN=3), window extraction fused; bf16 output.
// in = full inputs (2,20,56,56,3); out local (13,8,56,56,32) bf16.
// grid = 13*8*56, block (64,4). b = batch index.
// ---------------------------------------------------------------------------
__global__ __launch_bounds__(256)
void conv_c11_k(const float* __restrict__ in, const float* __restrict__ wgt,
                const float* __restrict__ bias, unsigned short* __restrict__ out, int b)
{
    constexpr int HH = 56, WW = 56, WP = 58, CINP = 4, COUT = 32;
    __shared__ float lds[3 * WP * CINP];
    const int blk = blockIdx.x;
    const int h = blk % HH;
    const int d = (blk / HH) % DD;
    const int n = blk / (HH * DD);          // window index = start frame t
    const int tx = threadIdx.x, ty = threadIdx.y;
    const int tid = ty * 64 + tx;

    for (int i = tid * 4; i < 3 * WP * CINP; i += 256 * 4)
        st4(&lds[i], float4{0.f, 0.f, 0.f, 0.f});

    const int c0 = ty * 8;
    float4 acc0 = {0, 0, 0, 0}, acc1 = {0, 0, 0, 0};

    for (int kd = 0; kd < 3; ++kd) {
        const int d2 = d + kd - 1;          // window-local depth (SAME padding)
        const bool dok = (d2 >= 0) && (d2 < DD);
        __syncthreads();
        if (dok) {
            const int frame = b * 20 + n + d2;   // global (b,t) frame
            for (int i = tid; i < 3 * WW; i += 256) {
                int kh = i / WW, w = i - kh * WW;
                int h2 = h + kh - 1;
                if (h2 >= 0 && h2 < HH) {
                    const float* src = &in[(((size_t)frame * HH + h2) * WW + w) * 3];
                    float* dst = &lds[(kh * WP + (w + 1)) * CINP];
                    dst[0] = src[0]; dst[1] = src[1]; dst[2] = src[2];
                }
            }
        }
        __syncthreads();
        if (dok && tx < WW) {
            #pragma unroll
            for (int kh = 0; kh < 3; ++kh) {
                #pragma unroll
                for (int kw = 0; kw < 3; ++kw) {
                    const float* lrow = &lds[(kh * WP + tx + kw) * CINP];
                    const float* wrow = &wgt[(((kd * 3 + kh) * 3 + kw) * 3) * COUT + c0];
                    #pragma unroll
                    for (int ci = 0; ci < 3; ++ci) {
                        float s = lrow[ci];
                        float4 wa = ld4(wrow + ci * COUT);
                        float4 wb = ld4(wrow + ci * COUT + 4);
                        fma4(acc0, s, wa);
                        fma4(acc1, s, wb);
                    }
                }
            }
        }
    }
    if (tx < WW) {
        float4 ba = ld4(bias + c0), bb = ld4(bias + c0 + 4);
        unsigned short o[8];
        o[0] = f2bf(fmaxf(0.f, acc0.x + ba.x));
        o[1] = f2bf(fmaxf(0.f, acc0.y + ba.y));
        o[2] = f2bf(fmaxf(0.f, acc0.z + ba.z));
        o[3] = f2bf(fmaxf(0.f, acc0.w + ba.w));
        o[4] = f2bf(fmaxf(0.f, acc1.x + bb.x));
        o[5] = f2bf(fmaxf(0.f, acc1.y + bb.y));
        o[6] = f2bf(fmaxf(0.f, acc1.z + bb.z));
        o[7] = f2bf(fmaxf(0.f, acc1.w + bb.w));
        size_t ob = ((((size_t)n * DD + d) * HH + h) * WW + tx) * COUT + c0;
        *(short8v*)&out[ob] = *(short8v*)o;
    }
}

// ---------------------------------------------------------------------------
// bf16 MFMA implicit-GEMM conv3d, SAME pad over (8,H,W), bias+relu fused.
// act: (NB,8,H,W,CIN) bf16; pk: packed bf16 weights; out: (NB,8,H,W,COUT) bf16.
// grid = NB*8*(H/HROWS), block 256 (4 waves).
// Block covers HROWS output h-rows x full W x all COUT.
// A staged in LDS (CINP=CIN+8 pad -> 2-way bank alias, free per m136).
// B read from global, fully coalesced (1 KiB per wave-load, L2-resident).
// Out-of-range A-rows (w>=W tiles) read garbage rows but only corrupt D-rows
// that the `w < W` guard discards (D row m depends only on A row m).
// ---------------------------------------------------------------------------
template<int CIN, int COUT, int H, int W, int HROWS>
__global__ __launch_bounds__(256)
void convmf_k(const unsigned short* __restrict__ act,
              const unsigned short* __restrict__ pk,
              const float* __restrict__ bias,
              unsigned short* __restrict__ out)
{
    constexpr int CPT = CIN / 32;           // k-chunks per tap
    constexpr int CHUNKS = 27 * CPT;
    constexpr int KH = HROWS + 2;           // h-rows staged per kd slice
    constexpr int ROWS = 3 * KH;
    constexpr int WP = W + 2;
    constexpr int CINP = CIN + 8;
    constexpr int TPH = (W + 15) / 16;      // 16-wide m-tiles per h-row
    constexpr int MTILES = HROWS * TPH;
    constexpr int NTILES = COUT / 16;
    constexpr int NTW = (MTILES * NTILES) / 4;   // n-tiles per wave
    constexpr int LDSE = ROWS * WP * CINP;
    static_assert((MTILES * NTILES) % 4 == 0, "tile mapping");
    __shared__ __align__(16) short sh[LDSE + 512];   // +512 slack for dead-lane reads

    const int HB = H / HROWS;
    const int blk = blockIdx.x;
    const int hblk = blk % HB;
    const int d = (blk / HB) % DD;
    const int bn = blk / (HB * DD);
    const int h0 = hblk * HROWS;
    const int tid = threadIdx.x;
    const int lane = tid & 63;
    const int wave = tid >> 6;
    const int l15 = lane & 15;
    const int l4 = lane >> 4;

    for (int i = tid * 8; i < LDSE + 512; i += 2048)
        *(short8v*)&sh[i] = short8v{0, 0, 0, 0, 0, 0, 0, 0};
    __syncthreads();

    constexpr int C8 = CIN / 8;
    constexpr int V8R = W * C8;             // 16B vectors per input row
    for (int i = tid; i < ROWS * V8R; i += 256) {
        int r = i / V8R;
        int q = i - r * V8R;
        int w = q / C8;
        int co = (q - w * C8) * 8;
        int kd = r / KH, khh = r - kd * KH;
        int dp = d + kd - 1, hp = h0 + khh - 1;
        if (dp >= 0 && dp < DD && hp >= 0 && hp < H) {
            short8v v = *(const short8v*)&act[((((size_t)bn * DD + dp) * H + hp) * W + w) * CIN + co];
            *(short8v*)&sh[(r * WP + w + 1) * CINP + co] = v;
        }
    }
    __syncthreads();

    const int mt = wave % MTILES;
    const int nt0 = (wave / MTILES) * NTW;
    const int h_off = mt / TPH;
    const int wseg = mt - h_off * TPH;

    f32x4 acc[NTW];
    #pragma unroll
    for (int t = 0; t < NTW; ++t) acc[t] = f32x4{0.f, 0.f, 0.f, 0.f};

    const short8v* bp = (const short8v*)pk;
    #pragma unroll 1
    for (int tap = 0; tap < 27; ++tap) {
        const int kd = tap / 9;
        const int rm = tap - kd * 9;
        const int kh = rm / 3;
        const int kw = rm - kh * 3;
        const int row = kd * KH + kh + h_off;
        const int wp = wseg * 16 + l15 + kw;
        const int abase = (row * WP + wp) * CINP + l4 * 8;
        #pragma unroll
        for (int cp = 0; cp < CPT; ++cp) {
            const int chunk = tap * CPT + cp;
            short8v a = *(const short8v*)&sh[abase + cp * 32];
            #pragma unroll
            for (int t = 0; t < NTW; ++t) {
                short8v b = bp[((size_t)(nt0 + t) * CHUNKS + chunk) * 64 + lane];
                acc[t] = __builtin_amdgcn_mfma_f32_16x16x32_bf16(a, b, acc[t], 0, 0, 0);
            }
        }
    }

    const int hout = h0 + h_off;
    #pragma unroll
    for (int t = 0; t < NTW; ++t) {
        const int cout = (nt0 + t) * 16 + l15;
        const float bi = bias[cout];
        #pragma unroll
        for (int r = 0; r < 4; ++r) {
            const int w = wseg * 16 + l4 * 4 + r;
            if (w < W) {
                float v = fmaxf(0.f, acc[t][r] + bi);
                out[((((size_t)bn * DD + d) * H + hout) * W + w) * COUT + cout] = f2bf(v);
            }
        }
    }
}

// ---------------------------------------------------------------------------
// MaxPool (1,2,2) valid, bf16. in (N8, 2HO, 2WO, C) -> out (N8, HO, WO, C).
// Post-relu values >= +0.0 -> unsigned-short compare == float compare.
// ---------------------------------------------------------------------------
template<int C, int HO, int WO>
__global__ __launch_bounds__(256)
void poolb_k(const unsigned short* __restrict__ in, unsigned short* __restrict__ out,
             int total8, size_t obase)
{
    constexpr int C8 = C / 8;
    for (int idx = blockIdx.x * 256 + threadIdx.x; idx < total8; idx += gridDim.x * 256) {
        int c8 = idx % C8;
        int t = idx / C8;
        int wo = t % WO; t /= WO;
        int ho = t % HO; t /= HO;            // t = nd
        size_t base = (((size_t)t * (2 * HO) + 2 * ho) * (2 * WO) + 2 * wo) * C + c8 * 8;
        short8v a = *(const short8v*)&in[base];
        short8v b = *(const short8v*)&in[base + C];
        short8v c = *(const short8v*)&in[base + (size_t)(2 * WO) * C];
        short8v e = *(const short8v*)&in[base + (size_t)(2 * WO) * C + C];
        unsigned short o[8];
        #pragma unroll
        for (int j = 0; j < 8; ++j) {
            unsigned short av = (unsigned short)a[j], bv = (unsigned short)b[j];
            unsigned short cv = (unsigned short)c[j], ev = (unsigned short)e[j];
            unsigned short m1 = av > bv ? av : bv;
            unsigned short m2 = cv > ev ? cv : ev;
            o[j] = m1 > m2 ? m1 : m2;
        }
        *(short8v*)&out[obase + (size_t)idx * 8] = *(short8v*)o;
    }
}

// ---------------------------------------------------------------------------
// GlobalAveragePooling3D: in (26,8,14,14,128) bf16 -> feats (26,128) f32.
// grid 26, block (128,8)
// ---------------------------------------------------------------------------
__global__ __launch_bounds__(1024)
void gapb_k(const unsigned short* __restrict__ in, float* __restrict__ outf)
{
    __shared__ float part[8][128];
    const int n = blockIdx.x;
    const int c = threadIdx.x;
    const int dy = threadIdx.y;
    float s = 0.f;
    const unsigned short* p = &in[((size_t)n * 1568 + dy * 196) * 128 + c];
    #pragma unroll 4
    for (int i = 0; i < 196; ++i) s += bf2f(p[(size_t)i * 128]);
    part[dy][c] = s;
    __syncthreads();
    if (dy == 0) {
        float t = 0.f;
        #pragma unroll
        for (int k = 0; k < 8; ++k) t += part[k][c];
        outf[n * 128 + c] = t * (1.f / 1568.f);
    }
}

// ---------------------------------------------------------------------------
// 3x GRU (Keras reset_after=true) + dense head + softmax. Single block of 384.
// feats: (2,13,128) f32. out: throw (2,64) then tori (2,2) = 132 floats.
// ---------------------------------------------------------------------------
__global__ __launch_bounds__(384)
void gru_head_k(const float* __restrict__ feats,
                const float* __restrict__ g1_wx, const float* __restrict__ g1_wh, const float* __restrict__ g1_b,
                const float* __restrict__ g2_wx, const float* __restrict__ g2_wh, const float* __restrict__ g2_b,
                const float* __restrict__ g3_wx, const float* __restrict__ g3_wh, const float* __restrict__ g3_b,
                const float* __restrict__ d1_w, const float* __restrict__ d1_b,
                const float* __restrict__ d2_w, const float* __restrict__ d2_b,
                const float* __restrict__ thr_w, const float* __restrict__ thr_b,
                const float* __restrict__ tori_w, const float* __restrict__ tori_b,
                float* __restrict__ out)
{
    __shared__ float xs[26 * 128];
    __shared__ float xp[13 * 2 * 192];
    __shared__ float seq[26 * 64];
    __shared__ float rec[2 * 192];
    __shared__ float hbuf[2 * 64];
    __shared__ float tmp[2 * 64];
    __shared__ float hd2[2 * 32];
    __shared__ float red[4];
    __shared__ float tl[4];
    const int tid = threadIdx.x;

    for (int i = tid; i < 26 * 128; i += 384) xs[i] = feats[i];
    __syncthreads();

    const float* WXs[3] = {g1_wx, g2_wx, g3_wx};
    const float* WHs[3] = {g1_wh, g2_wh, g3_wh};
    const float* GBs[3] = {g1_b, g2_b, g3_b};

    for (int layer = 0; layer < 3; ++layer) {
        const int K = (layer == 0) ? 128 : 64;
        const float* wx = WXs[layer];
        const float* wh = WHs[layer];
        const float* gb = GBs[layer];
        for (int i = tid; i < 13 * 2 * 192; i += 384) {
            int j = i % 192;
            int tb = i / 192;
            int b = tb % 2, t = tb / 2;
            const float* xrow = &xs[(b * 13 + t) * K];
            float s = gb[j];
            for (int k = 0; k < K; ++k) s = fmaf(xrow[k], wx[k * 192 + j], s);
            xp[(t * 2 + b) * 192 + j] = s;
        }
        if (tid < 128) hbuf[tid] = 0.f;
        __syncthreads();
        for (int t = 0; t < 13; ++t) {
            {
                int b = tid / 192, j = tid % 192;
                const float* hrow = &hbuf[b * 64];
                float s = gb[192 + j];
                #pragma unroll 4
                for (int k = 0; k < 64; ++k) s = fmaf(hrow[k], wh[k * 192 + j], s);
                rec[tid] = s;
            }
            __syncthreads();
            if (tid < 128) {
                int b = tid / 64, u = tid % 64;
                const float* xpt = &xp[(t * 2 + b) * 192];
                const float* rc = &rec[b * 192];
                float z = sigmoidf(xpt[u] + rc[u]);
                float r = sigmoidf(xpt[64 + u] + rc[64 + u]);
                float hh = tanhf(xpt[128 + u] + r * rc[128 + u]);
                float hn = z * hbuf[b * 64 + u] + (1.f - z) * hh;
                hbuf[b * 64 + u] = hn;
                seq[(b * 13 + t) * 64 + u] = hn;
            }
            __syncthreads();
        }
        if (layer < 2) {
            for (int i = tid; i < 26 * 64; i += 384) xs[i] = seq[i];
            __syncthreads();
        }
    }

    if (tid < 128) {
        int b = tid / 64, u = tid % 64;
        float s = d1_b[u];
        for (int k = 0; k < 64; ++k) s = fmaf(hbuf[b * 64 + k], d1_w[k * 64 + u], s);
        tmp[b * 64 + u] = fmaxf(s, 0.f);
    }
    __syncthreads();
    if (tid < 64) {
        int b = tid / 32, u = tid % 32;
        float s = d2_b[u];
        for (int k = 0; k < 64; ++k) s = fmaf(tmp[b * 64 + k], d2_w[k * 32 + u], s);
        hd2[b * 32 + u] = fmaxf(s, 0.f);
    }
    __syncthreads();
    if (tid < 128) {
        int b = tid / 64, u = tid % 64;
        float s = thr_b[u];
        for (int k = 0; k < 32; ++k) s = fmaf(hd2[b * 32 + k], thr_w[k * 64 + u], s);
        tmp[b * 64 + u] = s;
    }
    if (tid >= 128 && tid < 132) {
        int i = tid - 128;
        int b = i >> 1, u = i & 1;
        float s = tori_b[u];
        for (int k = 0; k < 32; ++k) s = fmaf(hd2[b * 32 + k], tori_w[k * 2 + u], s);
        tl[i] = s;
    }
    __syncthreads();
    if (tid < 2) {
        float m = -1e30f;
        for (int u = 0; u < 64; ++u) m = fmaxf(m, tmp[tid * 64 + u]);
        float s = 0.f;
        for (int u = 0; u < 64; ++u) s += expf(tmp[tid * 64 + u] - m);
        red[tid * 2] = m;
        red[tid * 2 + 1] = s;
    }
    __syncthreads();
    if (tid < 128) {
        int b = tid >> 6;
        out[tid] = expf(tmp[tid] - red[b * 2]) / red[b * 2 + 1];
    }
    if (tid >= 128 && tid < 130) {
        int b = tid - 128;
        float a = tl[b * 2], c = tl[b * 2 + 1];
        float m = fmaxf(a, c);
        float e0 = expf(a - m), e1 = expf(c - m);
        float inv = 1.f / (e0 + e1);
        out[128 + b * 2 + 0] = e0 * inv;
        out[128 + b * 2 + 1] = e1 * inv;
    }
}

// ---------------------------------------------------------------------------
extern "C" void kernel_launch(void* const* d_in, const int* in_sizes, int n_in,
                              void* d_out, int out_size, void* d_ws, size_t ws_size,
                              hipStream_t stream) {
    const float* inputs = (const float*)d_in[0];
    const float* c11_k = (const float*)d_in[1];  const float* c11_b = (const float*)d_in[2];
    const float* c12_k = (const float*)d_in[3];  const float* c12_b = (const float*)d_in[4];
    const float* c21_k = (const float*)d_in[5];  const float* c21_b = (const float*)d_in[6];
    const float* c22_k = (const float*)d_in[7];  const float* c22_b = (const float*)d_in[8];
    const float* c31_k = (const float*)d_in[9];  const float* c31_b = (const float*)d_in[10];
    const float* c32_k = (const float*)d_in[11]; const float* c32_b = (const float*)d_in[12];
    const float* g1_wx = (const float*)d_in[13]; const float* g1_wh = (const float*)d_in[14]; const float* g1_b = (const float*)d_in[15];
    const float* g2_wx = (const float*)d_in[16]; const float* g2_wh = (const float*)d_in[17]; const float* g2_b = (const float*)d_in[18];
    const float* g3_wx = (const float*)d_in[19]; const float* g3_wh = (const float*)d_in[20]; const float* g3_b = (const float*)d_in[21];
    const float* d1_w = (const float*)d_in[22];  const float* d1_b = (const float*)d_in[23];
    const float* d2_w = (const float*)d_in[24];  const float* d2_b = (const float*)d_in[25];
    const float* thr_w = (const float*)d_in[26]; const float* thr_b = (const float*)d_in[27];
    const float* tori_w = (const float*)d_in[28]; const float* tori_b = (const float*)d_in[29];

    typedef unsigned short u16;
    char* base = (char*)d_ws;
    // packed weights (bf16 elems): c12 27648, c21 55296, c22 110592, c31 221184, c32 442368
    u16* pk12 = (u16*)base;
    u16* pk21 = pk12 + 27648;
    u16* pk22 = pk21 + 55296;
    u16* pk31 = pk22 + 110592;
    u16* pk32 = pk31 + 221184;                 // end elems 857088 -> 1,714,176 B
    float* feats = (float*)(base + 1714176);   // 13,312 B
    u16* p1 = (u16*)(base + 1727488);          // (26,8,28,28,32) bf16 = 10,436,608 B
    u16* hA = (u16*)(base + 12164096);         // 20,873,216 B
    u16* hB = (u16*)(base + 33037312);         // 20,873,216 B; total 53,910,528 B
    float* out = (float*)d_out;

    // pack weights (graph-safe, recomputed every launch)
    pack_w_k<<<108, 256, 0, stream>>>(c12_k, pk12, 27, 32, 27648);
    pack_w_k<<<216, 256, 0, stream>>>(c21_k, pk21, 27, 64, 55296);
    pack_w_k<<<432, 256, 0, stream>>>(c22_k, pk22, 54, 64, 110592);
    pack_w_k<<<864, 256, 0, stream>>>(c31_k, pk31, 54, 128, 221184);
    pack_w_k<<<1728, 256, 0, stream>>>(c32_k, pk32, 108, 128, 442368);

    // stage 1 in two batch halves (keeps peak ws at 53.9 MB)
    for (int b = 0; b < 2; ++b) {
        conv_c11_k<<<13 * 8 * 56, dim3(64, 4), 0, stream>>>(inputs, c11_k, c11_b, hA, b);
        convmf_k<32, 32, 56, 56, 1><<<13 * 8 * 56, 256, 0, stream>>>(hA, pk12, c12_b, hB);
        poolb_k<32, 28, 28><<<1274, 256, 0, stream>>>(hB, p1, 13 * 8 * 28 * 28 * 4, (size_t)b * 2609152);
    }
    // stages 2-3 full batch (26 sequences)
    convmf_k<32, 64, 28, 28, 2><<<26 * 8 * 14, 256, 0, stream>>>(p1, pk21, c21_b, hA);
    convmf_k<64, 64, 28, 28, 1><<<26 * 8 * 28, 256, 0, stream>>>(hA, pk22, c22_b, hB);
    poolb_k<64, 14, 14><<<1274, 256, 0, stream>>>(hB, p1, 26 * 8 * 14 * 14 * 8, 0);
    convmf_k<64, 128, 14, 14, 2><<<26 * 8 * 7, 256, 0, stream>>>(p1, pk31, c31_b, hA);
    convmf_k<128, 128, 14, 14, 2><<<26 * 8 * 7, 256, 0, stream>>>(hA, pk32, c32_b, hB);
    gapb_k<<<26, dim3(128, 8), 0, stream>>>(hB, feats);

    gru_head_k<<<1, 384, 0, stream>>>(feats,
        g1_wx, g1_wh, g1_b, g2_wx, g2_wh, g2_b, g3_wx, g3_wh, g3_b,
        d1_w, d1_b, d2_w, d2_b, thr_w, thr_b, tori_w, tori_b, out);
}

// Round 10
// 925.276 us; speedup vs baseline: 10.9588x; 1.4295x over previous
//
#include <hip/hip_runtime.h>
#include <math.h>

#define DD 8

typedef __attribute__((ext_vector_type(8))) short short8v;
typedef __attribute__((ext_vector_type(4))) float f32x4;

__device__ __forceinline__ float4 ld4(const float* p) {
    return *reinterpret_cast<const float4*>(p);
}
__device__ __forceinline__ void st4(float* p, float4 v) {
    *reinterpret_cast<float4*>(p) = v;
}
__device__ __forceinline__ void fma4(float4& a, float s, float4 w) {
    a.x = fmaf(s, w.x, a.x);
    a.y = fmaf(s, w.y, a.y);
    a.z = fmaf(s, w.z, a.z);
    a.w = fmaf(s, w.w, a.w);
}
__device__ __forceinline__ float sigmoidf(float x) { return 1.f / (1.f + expf(-x)); }

__device__ __forceinline__ float bf2f(unsigned short u) {
    union { unsigned int i; float f; } v; v.i = ((unsigned int)u) << 16; return v.f;
}
__device__ __forceinline__ unsigned short f2bf(float f) {
    union { float f; unsigned int i; } v; v.f = f;
    unsigned int r = v.i + 0x7FFFu + ((v.i >> 16) & 1u);
    return (unsigned short)(r >> 16);
}

// ---------------------------------------------------------------------------
// Weight pre-pack: wgt (K=27*CIN, COUT) fp32 -> bf16 fragments.
// ---------------------------------------------------------------------------
__global__ __launch_bounds__(256)
void pack_w_k(const float* __restrict__ wgt, unsigned short* __restrict__ pk,
              int chunks, int cout_n, int total)
{
    for (int id = blockIdx.x * 256 + threadIdx.x; id < total; id += gridDim.x * 256) {
        int j = id & 7;
        int l = (id >> 3) & 63;
        int rest = id >> 9;
        int chunk = rest % chunks;
        int nt = rest / chunks;
        int k = chunk * 32 + ((l >> 4) << 3) + j;
        int cout = nt * 16 + (l & 15);
        pk[id] = f2bf(wgt[(size_t)k * cout_n + cout]);
    }
}

// ---------------------------------------------------------------------------
// First conv fp32 direct (CIN=3), window extraction fused; bf16 output.
// ---------------------------------------------------------------------------
__global__ __launch_bounds__(256)
void conv_c11_k(const float* __restrict__ in, const float* __restrict__ wgt,
                const float* __restrict__ bias, unsigned short* __restrict__ out, int b)
{
    constexpr int HH = 56, WW = 56, WP = 58, CINP = 4, COUT = 32;
    __shared__ float lds[3 * WP * CINP];
    const int blk = blockIdx.x;
    const int h = blk % HH;
    const int d = (blk / HH) % DD;
    const int n = blk / (HH * DD);          // window index = start frame t
    const int tx = threadIdx.x, ty = threadIdx.y;
    const int tid = ty * 64 + tx;

    for (int i = tid * 4; i < 3 * WP * CINP; i += 256 * 4)
        st4(&lds[i], float4{0.f, 0.f, 0.f, 0.f});

    const int c0 = ty * 8;
    float4 acc0 = {0, 0, 0, 0}, acc1 = {0, 0, 0, 0};

    for (int kd = 0; kd < 3; ++kd) {
        const int d2 = d + kd - 1;          // window-local depth (SAME padding)
        const bool dok = (d2 >= 0) && (d2 < DD);
        __syncthreads();
        if (dok) {
            const int frame = b * 20 + n + d2;   // global (b,t) frame
            for (int i = tid; i < 3 * WW; i += 256) {
                int kh = i / WW, w = i - kh * WW;
                int h2 = h + kh - 1;
                if (h2 >= 0 && h2 < HH) {
                    const float* src = &in[(((size_t)frame * HH + h2) * WW + w) * 3];
                    float* dst = &lds[(kh * WP + (w + 1)) * CINP];
                    dst[0] = src[0]; dst[1] = src[1]; dst[2] = src[2];
                }
            }
        }
        __syncthreads();
        if (dok && tx < WW) {
            #pragma unroll
            for (int kh = 0; kh < 3; ++kh) {
                #pragma unroll
                for (int kw = 0; kw < 3; ++kw) {
                    const float* lrow = &lds[(kh * WP + tx + kw) * CINP];
                    const float* wrow = &wgt[(((kd * 3 + kh) * 3 + kw) * 3) * COUT + c0];
                    #pragma unroll
                    for (int ci = 0; ci < 3; ++ci) {
                        float s = lrow[ci];
                        float4 wa = ld4(wrow + ci * COUT);
                        float4 wb = ld4(wrow + ci * COUT + 4);
                        fma4(acc0, s, wa);
                        fma4(acc1, s, wb);
                    }
                }
            }
        }
    }
    if (tx < WW) {
        float4 ba = ld4(bias + c0), bb = ld4(bias + c0 + 4);
        unsigned short o[8];
        o[0] = f2bf(fmaxf(0.f, acc0.x + ba.x));
        o[1] = f2bf(fmaxf(0.f, acc0.y + ba.y));
        o[2] = f2bf(fmaxf(0.f, acc0.z + ba.z));
        o[3] = f2bf(fmaxf(0.f, acc0.w + ba.w));
        o[4] = f2bf(fmaxf(0.f, acc1.x + bb.x));
        o[5] = f2bf(fmaxf(0.f, acc1.y + bb.y));
        o[6] = f2bf(fmaxf(0.f, acc1.z + bb.z));
        o[7] = f2bf(fmaxf(0.f, acc1.w + bb.w));
        size_t ob = ((((size_t)n * DD + d) * HH + h) * WW + tx) * COUT + c0;
        *(short8v*)&out[ob] = *(short8v*)o;
    }
}

// ---------------------------------------------------------------------------
// bf16 MFMA implicit-GEMM conv3d (verified round 6, unchanged).
// ---------------------------------------------------------------------------
template<int CIN, int COUT, int H, int W, int HROWS>
__global__ __launch_bounds__(256)
void convmf_k(const unsigned short* __restrict__ act,
              const unsigned short* __restrict__ pk,
              const float* __restrict__ bias,
              unsigned short* __restrict__ out)
{
    constexpr int CPT = CIN / 32;           // k-chunks per tap
    constexpr int CHUNKS = 27 * CPT;
    constexpr int KH = HROWS + 2;           // h-rows staged per kd slice
    constexpr int ROWS = 3 * KH;
    constexpr int WP = W + 2;
    constexpr int CINP = CIN + 8;
    constexpr int TPH = (W + 15) / 16;      // 16-wide m-tiles per h-row
    constexpr int MTILES = HROWS * TPH;
    constexpr int NTILES = COUT / 16;
    constexpr int NTW = (MTILES * NTILES) / 4;   // n-tiles per wave
    constexpr int LDSE = ROWS * WP * CINP;
    static_assert((MTILES * NTILES) % 4 == 0, "tile mapping");
    __shared__ __align__(16) short sh[LDSE + 512];   // +512 slack for dead-lane reads

    const int HB = H / HROWS;
    const int blk = blockIdx.x;
    const int hblk = blk % HB;
    const int d = (blk / HB) % DD;
    const int bn = blk / (HB * DD);
    const int h0 = hblk * HROWS;
    const int tid = threadIdx.x;
    const int lane = tid & 63;
    const int wave = tid >> 6;
    const int l15 = lane & 15;
    const int l4 = lane >> 4;

    for (int i = tid * 8; i < LDSE + 512; i += 2048)
        *(short8v*)&sh[i] = short8v{0, 0, 0, 0, 0, 0, 0, 0};
    __syncthreads();

    constexpr int C8 = CIN / 8;
    constexpr int V8R = W * C8;             // 16B vectors per input row
    for (int i = tid; i < ROWS * V8R; i += 256) {
        int r = i / V8R;
        int q = i - r * V8R;
        int w = q / C8;
        int co = (q - w * C8) * 8;
        int kd = r / KH, khh = r - kd * KH;
        int dp = d + kd - 1, hp = h0 + khh - 1;
        if (dp >= 0 && dp < DD && hp >= 0 && hp < H) {
            short8v v = *(const short8v*)&act[((((size_t)bn * DD + dp) * H + hp) * W + w) * CIN + co];
            *(short8v*)&sh[(r * WP + w + 1) * CINP + co] = v;
        }
    }
    __syncthreads();

    const int mt = wave % MTILES;
    const int nt0 = (wave / MTILES) * NTW;
    const int h_off = mt / TPH;
    const int wseg = mt - h_off * TPH;

    f32x4 acc[NTW];
    #pragma unroll
    for (int t = 0; t < NTW; ++t) acc[t] = f32x4{0.f, 0.f, 0.f, 0.f};

    const short8v* bp = (const short8v*)pk;
    #pragma unroll 1
    for (int tap = 0; tap < 27; ++tap) {
        const int kd = tap / 9;
        const int rm = tap - kd * 9;
        const int kh = rm / 3;
        const int kw = rm - kh * 3;
        const int row = kd * KH + kh + h_off;
        const int wp = wseg * 16 + l15 + kw;
        const int abase = (row * WP + wp) * CINP + l4 * 8;
        #pragma unroll
        for (int cp = 0; cp < CPT; ++cp) {
            const int chunk = tap * CPT + cp;
            short8v a = *(const short8v*)&sh[abase + cp * 32];
            #pragma unroll
            for (int t = 0; t < NTW; ++t) {
                short8v b = bp[((size_t)(nt0 + t) * CHUNKS + chunk) * 64 + lane];
                acc[t] = __builtin_amdgcn_mfma_f32_16x16x32_bf16(a, b, acc[t], 0, 0, 0);
            }
        }
    }

    const int hout = h0 + h_off;
    #pragma unroll
    for (int t = 0; t < NTW; ++t) {
        const int cout = (nt0 + t) * 16 + l15;
        const float bi = bias[cout];
        #pragma unroll
        for (int r = 0; r < 4; ++r) {
            const int w = wseg * 16 + l4 * 4 + r;
            if (w < W) {
                float v = fmaxf(0.f, acc[t][r] + bi);
                out[((((size_t)bn * DD + d) * H + hout) * W + w) * COUT + cout] = f2bf(v);
            }
        }
    }
}

// ---------------------------------------------------------------------------
// MaxPool (1,2,2) valid, bf16 (unchanged).
// ---------------------------------------------------------------------------
template<int C, int HO, int WO>
__global__ __launch_bounds__(256)
void poolb_k(const unsigned short* __restrict__ in, unsigned short* __restrict__ out,
             int total8, size_t obase)
{
    constexpr int C8 = C / 8;
    for (int idx = blockIdx.x * 256 + threadIdx.x; idx < total8; idx += gridDim.x * 256) {
        int c8 = idx % C8;
        int t = idx / C8;
        int wo = t % WO; t /= WO;
        int ho = t % HO; t /= HO;            // t = nd
        size_t base = (((size_t)t * (2 * HO) + 2 * ho) * (2 * WO) + 2 * wo) * C + c8 * 8;
        short8v a = *(const short8v*)&in[base];
        short8v b = *(const short8v*)&in[base + C];
        short8v c = *(const short8v*)&in[base + (size_t)(2 * WO) * C];
        short8v e = *(const short8v*)&in[base + (size_t)(2 * WO) * C + C];
        unsigned short o[8];
        #pragma unroll
        for (int j = 0; j < 8; ++j) {
            unsigned short av = (unsigned short)a[j], bv = (unsigned short)b[j];
            unsigned short cv = (unsigned short)c[j], ev = (unsigned short)e[j];
            unsigned short m1 = av > bv ? av : bv;
            unsigned short m2 = cv > ev ? cv : ev;
            o[j] = m1 > m2 ? m1 : m2;
        }
        *(short8v*)&out[obase + (size_t)idx * 8] = *(short8v*)o;
    }
}

// ---------------------------------------------------------------------------
// GlobalAveragePooling3D (unchanged).
// ---------------------------------------------------------------------------
__global__ __launch_bounds__(1024)
void gapb_k(const unsigned short* __restrict__ in, float* __restrict__ outf)
{
    __shared__ float part[8][128];
    const int n = blockIdx.x;
    const int c = threadIdx.x;
    const int dy = threadIdx.y;
    float s = 0.f;
    const unsigned short* p = &in[((size_t)n * 1568 + dy * 196) * 128 + c];
    #pragma unroll 4
    for (int i = 0; i < 196; ++i) s += bf2f(p[(size_t)i * 128]);
    part[dy][c] = s;
    __syncthreads();
    if (dy == 0) {
        float t = 0.f;
        #pragma unroll
        for (int k = 0; k < 8; ++k) t += part[k][c];
        outf[n * 128 + c] = t * (1.f / 1568.f);
    }
}

// ---------------------------------------------------------------------------
// Layer-1 input projection (parallel): xp1[(t*2+b)*192+j] =
//   feats[(b*13+t)]·g1_wx[:,j] + g1_b[0][j].   grid 26, block 192.
// ---------------------------------------------------------------------------
__global__ __launch_bounds__(192)
void xp1_k(const float* __restrict__ feats, const float* __restrict__ wx,
           const float* __restrict__ gb, float* __restrict__ xp1)
{
    __shared__ float xrow[128];
    const int tb = blockIdx.x;           // t*2 + b
    const int b = tb & 1, t = tb >> 1;
    const int j = threadIdx.x;
    if (j < 128) xrow[j] = feats[(b * 13 + t) * 128 + j];
    __syncthreads();
    float s = gb[j];
    #pragma unroll 16
    for (int k = 0; k < 128; ++k) s = fmaf(xrow[k], wx[k * 192 + j], s);
    xp1[tb * 192 + j] = s;
}

// ---------------------------------------------------------------------------
// GRU scan (3 layers) + head, single block 384. All weights staged in LDS
// (bf16, 24.5 KB buffer reused per phase: wx -> xp compute -> wh -> scan).
// Recurrent matvec runs entirely from LDS: 64-FMA chain per step.
// ---------------------------------------------------------------------------
__global__ __launch_bounds__(384)
void gru2_k(const float* __restrict__ xp1,
            const float* __restrict__ g1_wh, const float* __restrict__ g1_b,
            const float* __restrict__ g2_wx, const float* __restrict__ g2_wh, const float* __restrict__ g2_b,
            const float* __restrict__ g3_wx, const float* __restrict__ g3_wh, const float* __restrict__ g3_b,
            const float* __restrict__ d1_w, const float* __restrict__ d1_b,
            const float* __restrict__ d2_w, const float* __restrict__ d2_b,
            const float* __restrict__ thr_w, const float* __restrict__ thr_b,
            const float* __restrict__ tori_w, const float* __restrict__ tori_b,
            float* __restrict__ out)
{
    __shared__ float xp[13 * 2 * 192];          // 19,968 B
    __shared__ float seq[26 * 64];              //  6,656 B
    __shared__ unsigned short wbuf[64 * 192];   // 24,576 B (bf16 weights)
    __shared__ float hbuf[2 * 64];
    __shared__ float rec[2 * 192];
    __shared__ float gbr[192];
    __shared__ float tmp[2 * 64];
    __shared__ float hd2[2 * 32];
    __shared__ float red[4];
    __shared__ float tl[4];
    const int tid = threadIdx.x;
    const int jj = tid % 192;
    const int bb = tid / 192;

    for (int i = tid; i < 13 * 2 * 192; i += 384) xp[i] = xp1[i];

    const float* WHs[3] = {g1_wh, g2_wh, g3_wh};
    const float* WXs[3] = {nullptr, g2_wx, g3_wx};
    const float* GBs[3] = {g1_b, g2_b, g3_b};

    for (int layer = 0; layer < 3; ++layer) {
        const float* gb = GBs[layer];
        if (layer > 0) {
            // stage wx (bf16) and compute xp for all t from seq (LDS)
            const float* wx = WXs[layer];
            for (int i = tid; i < 64 * 192; i += 384) wbuf[i] = f2bf(wx[i]);
            __syncthreads();
            const float bi = gb[jj];
            for (int t = 0; t < 13; ++t) {
                const float* xr = &seq[(bb * 13 + t) * 64];
                float s = bi;
                #pragma unroll 8
                for (int k = 0; k < 64; ++k) s = fmaf(xr[k], bf2f(wbuf[k * 192 + jj]), s);
                xp[(t * 2 + bb) * 192 + jj] = s;
            }
            __syncthreads();
        }
        // stage wh (bf16) + recurrent bias, init h
        const float* wh = WHs[layer];
        for (int i = tid; i < 64 * 192; i += 384) wbuf[i] = f2bf(wh[i]);
        if (tid < 192) gbr[tid] = gb[192 + tid];
        if (tid < 128) hbuf[tid] = 0.f;
        __syncthreads();
        for (int t = 0; t < 13; ++t) {
            {
                const float* hr = &hbuf[bb * 64];
                float s = gbr[jj];
                #pragma unroll 8
                for (int k = 0; k < 64; ++k) s = fmaf(hr[k], bf2f(wbuf[k * 192 + jj]), s);
                rec[tid] = s;
            }
            __syncthreads();
            if (tid < 128) {
                int b = tid / 64, u = tid % 64;
                const float* xpt = &xp[(t * 2 + b) * 192];
                const float* rc = &rec[b * 192];
                float z = sigmoidf(xpt[u] + rc[u]);
                float r = sigmoidf(xpt[64 + u] + rc[64 + u]);
                float hh = tanhf(xpt[128 + u] + r * rc[128 + u]);
                float hn = z * hbuf[b * 64 + u] + (1.f - z) * hh;
                hbuf[b * 64 + u] = hn;
                seq[(b * 13 + t) * 64 + u] = hn;
            }
            __syncthreads();
        }
    }

    // dense head (tiny; weights L2-hot)
    if (tid < 128) {
        int b = tid / 64, u = tid % 64;
        float s = d1_b[u];
        for (int k = 0; k < 64; ++k) s = fmaf(hbuf[b * 64 + k], d1_w[k * 64 + u], s);
        tmp[b * 64 + u] = fmaxf(s, 0.f);
    }
    __syncthreads();
    if (tid < 64) {
        int b = tid / 32, u = tid % 32;
        float s = d2_b[u];
        for (int k = 0; k < 64; ++k) s = fmaf(tmp[b * 64 + k], d2_w[k * 32 + u], s);
        hd2[b * 32 + u] = fmaxf(s, 0.f);
    }
    __syncthreads();
    if (tid < 128) {
        int b = tid / 64, u = tid % 64;
        float s = thr_b[u];
        for (int k = 0; k < 32; ++k) s = fmaf(hd2[b * 32 + k], thr_w[k * 64 + u], s);
        tmp[b * 64 + u] = s;
    }
    if (tid >= 128 && tid < 132) {
        int i = tid - 128;
        int b = i >> 1, u = i & 1;
        float s = tori_b[u];
        for (int k = 0; k < 32; ++k) s = fmaf(hd2[b * 32 + k], tori_w[k * 2 + u], s);
        tl[i] = s;
    }
    __syncthreads();
    if (tid < 2) {
        float m = -1e30f;
        for (int u = 0; u < 64; ++u) m = fmaxf(m, tmp[tid * 64 + u]);
        float s = 0.f;
        for (int u = 0; u < 64; ++u) s += expf(tmp[tid * 64 + u] - m);
        red[tid * 2] = m;
        red[tid * 2 + 1] = s;
    }
    __syncthreads();
    if (tid < 128) {
        int b = tid >> 6;
        out[tid] = expf(tmp[tid] - red[b * 2]) / red[b * 2 + 1];
    }
    if (tid >= 128 && tid < 130) {
        int b = tid - 128;
        float a = tl[b * 2], c = tl[b * 2 + 1];
        float m = fmaxf(a, c);
        float e0 = expf(a - m), e1 = expf(c - m);
        float inv = 1.f / (e0 + e1);
        out[128 + b * 2 + 0] = e0 * inv;
        out[128 + b * 2 + 1] = e1 * inv;
    }
}

// ---------------------------------------------------------------------------
extern "C" void kernel_launch(void* const* d_in, const int* in_sizes, int n_in,
                              void* d_out, int out_size, void* d_ws, size_t ws_size,
                              hipStream_t stream) {
    const float* inputs = (const float*)d_in[0];
    const float* c11_k = (const float*)d_in[1];  const float* c11_b = (const float*)d_in[2];
    const float* c12_k = (const float*)d_in[3];  const float* c12_b = (const float*)d_in[4];
    const float* c21_k = (const float*)d_in[5];  const float* c21_b = (const float*)d_in[6];
    const float* c22_k = (const float*)d_in[7];  const float* c22_b = (const float*)d_in[8];
    const float* c31_k = (const float*)d_in[9];  const float* c31_b = (const float*)d_in[10];
    const float* c32_k = (const float*)d_in[11]; const float* c32_b = (const float*)d_in[12];
    const float* g1_wx = (const float*)d_in[13]; const float* g1_wh = (const float*)d_in[14]; const float* g1_b = (const float*)d_in[15];
    const float* g2_wx = (const float*)d_in[16]; const float* g2_wh = (const float*)d_in[17]; const float* g2_b = (const float*)d_in[18];
    const float* g3_wx = (const float*)d_in[19]; const float* g3_wh = (const float*)d_in[20]; const float* g3_b = (const float*)d_in[21];
    const float* d1_w = (const float*)d_in[22];  const float* d1_b = (const float*)d_in[23];
    const float* d2_w = (const float*)d_in[24];  const float* d2_b = (const float*)d_in[25];
    const float* thr_w = (const float*)d_in[26]; const float* thr_b = (const float*)d_in[27];
    const float* tori_w = (const float*)d_in[28]; const float* tori_b = (const float*)d_in[29];

    typedef unsigned short u16;
    char* base = (char*)d_ws;
    // packed weights (bf16 elems): c12 27648, c21 55296, c22 110592, c31 221184, c32 442368
    u16* pk12 = (u16*)base;
    u16* pk21 = pk12 + 27648;
    u16* pk22 = pk21 + 55296;
    u16* pk31 = pk22 + 110592;
    u16* pk32 = pk31 + 221184;                 // end 1,714,176 B
    float* feats = (float*)(base + 1714176);   // 13,312 B
    float* xp1   = (float*)(base + 1727488);   // 19,968 B
    u16* p1 = (u16*)(base + 1747456);          // 10,436,608 B
    u16* hA = (u16*)(base + 12184064);         // 20,873,216 B
    u16* hB = (u16*)(base + 33057280);         // 20,873,216 B; total 53,930,496 B
    float* out = (float*)d_out;

    // pack weights (graph-safe, recomputed every launch)
    pack_w_k<<<108, 256, 0, stream>>>(c12_k, pk12, 27, 32, 27648);
    pack_w_k<<<216, 256, 0, stream>>>(c21_k, pk21, 27, 64, 55296);
    pack_w_k<<<432, 256, 0, stream>>>(c22_k, pk22, 54, 64, 110592);
    pack_w_k<<<864, 256, 0, stream>>>(c31_k, pk31, 54, 128, 221184);
    pack_w_k<<<1728, 256, 0, stream>>>(c32_k, pk32, 108, 128, 442368);

    // stage 1 in two batch halves (keeps peak ws at 53.9 MB)
    for (int b = 0; b < 2; ++b) {
        conv_c11_k<<<13 * 8 * 56, dim3(64, 4), 0, stream>>>(inputs, c11_k, c11_b, hA, b);
        convmf_k<32, 32, 56, 56, 1><<<13 * 8 * 56, 256, 0, stream>>>(hA, pk12, c12_b, hB);
        poolb_k<32, 28, 28><<<1274, 256, 0, stream>>>(hB, p1, 13 * 8 * 28 * 28 * 4, (size_t)b * 2609152);
    }
    // stages 2-3 full batch (26 sequences)
    convmf_k<32, 64, 28, 28, 2><<<26 * 8 * 14, 256, 0, stream>>>(p1, pk21, c21_b, hA);
    convmf_k<64, 64, 28, 28, 1><<<26 * 8 * 28, 256, 0, stream>>>(hA, pk22, c22_b, hB);
    poolb_k<64, 14, 14><<<1274, 256, 0, stream>>>(hB, p1, 26 * 8 * 14 * 14 * 8, 0);
    convmf_k<64, 128, 14, 14, 2><<<26 * 8 * 7, 256, 0, stream>>>(p1, pk31, c31_b, hA);
    convmf_k<128, 128, 14, 14, 2><<<26 * 8 * 7, 256, 0, stream>>>(hA, pk32, c32_b, hB);
    gapb_k<<<26, dim3(128, 8), 0, stream>>>(hB, feats);

    // GRU: parallel layer-1 projection, then LDS-staged scan
    xp1_k<<<26, 192, 0, stream>>>(feats, g1_wx, g1_b, xp1);
    gru2_k<<<1, 384, 0, stream>>>(xp1,
        g1_wh, g1_b, g2_wx, g2_wh, g2_b, g3_wx, g3_wh, g3_b,
        d1_w, d1_b, d2_w, d2_b, thr_w, thr_b, tori_w, tori_b, out);
}

// Round 12
// 778.569 us; speedup vs baseline: 13.0237x; 1.1884x over previous
//
#include <hip/hip_runtime.h>
#include <math.h>

#define DD 8

typedef __attribute__((ext_vector_type(8))) short short8v;
typedef __attribute__((ext_vector_type(4))) float f32x4;

__device__ __forceinline__ float4 ld4(const float* p) {
    return *reinterpret_cast<const float4*>(p);
}
__device__ __forceinline__ void st4(float* p, float4 v) {
    *reinterpret_cast<float4*>(p) = v;
}
__device__ __forceinline__ void fma4(float4& a, float s, float4 w) {
    a.x = fmaf(s, w.x, a.x);
    a.y = fmaf(s, w.y, a.y);
    a.z = fmaf(s, w.z, a.z);
    a.w = fmaf(s, w.w, a.w);
}
__device__ __forceinline__ float sigmoidf(float x) { return 1.f / (1.f + expf(-x)); }

__device__ __forceinline__ float bf2f(unsigned short u) {
    union { unsigned int i; float f; } v; v.i = ((unsigned int)u) << 16; return v.f;
}
__device__ __forceinline__ unsigned short f2bf(float f) {
    union { float f; unsigned int i; } v; v.f = f;
    unsigned int r = v.i + 0x7FFFu + ((v.i >> 16) & 1u);
    return (unsigned short)(r >> 16);
}

// ---------------------------------------------------------------------------
// Weight pre-pack: wgt (K=27*CIN, COUT) fp32 -> bf16 fragments (unchanged).
// ---------------------------------------------------------------------------
__global__ __launch_bounds__(256)
void pack_w_k(const float* __restrict__ wgt, unsigned short* __restrict__ pk,
              int chunks, int cout_n, int total)
{
    for (int id = blockIdx.x * 256 + threadIdx.x; id < total; id += gridDim.x * 256) {
        int j = id & 7;
        int l = (id >> 3) & 63;
        int rest = id >> 9;
        int chunk = rest % chunks;
        int nt = rest / chunks;
        int k = chunk * 32 + ((l >> 4) << 3) + j;
        int cout = nt * 16 + (l & 15);
        pk[id] = f2bf(wgt[(size_t)k * cout_n + cout]);
    }
}

// ---------------------------------------------------------------------------
// First conv fp32 direct (CIN=3), window extraction fused; bf16 output
// (unchanged, verified round 6).
// ---------------------------------------------------------------------------
__global__ __launch_bounds__(256)
void conv_c11_k(const float* __restrict__ in, const float* __restrict__ wgt,
                const float* __restrict__ bias, unsigned short* __restrict__ out, int b)
{
    constexpr int HH = 56, WW = 56, WP = 58, CINP = 4, COUT = 32;
    __shared__ float lds[3 * WP * CINP];
    const int blk = blockIdx.x;
    const int h = blk % HH;
    const int d = (blk / HH) % DD;
    const int n = blk / (HH * DD);          // window index = start frame t
    const int tx = threadIdx.x, ty = threadIdx.y;
    const int tid = ty * 64 + tx;

    for (int i = tid * 4; i < 3 * WP * CINP; i += 256 * 4)
        st4(&lds[i], float4{0.f, 0.f, 0.f, 0.f});

    const int c0 = ty * 8;
    float4 acc0 = {0, 0, 0, 0}, acc1 = {0, 0, 0, 0};

    for (int kd = 0; kd < 3; ++kd) {
        const int d2 = d + kd - 1;          // window-local depth (SAME padding)
        const bool dok = (d2 >= 0) && (d2 < DD);
        __syncthreads();
        if (dok) {
            const int frame = b * 20 + n + d2;   // global (b,t) frame
            for (int i = tid; i < 3 * WW; i += 256) {
                int kh = i / WW, w = i - kh * WW;
                int h2 = h + kh - 1;
                if (h2 >= 0 && h2 < HH) {
                    const float* src = &in[(((size_t)frame * HH + h2) * WW + w) * 3];
                    float* dst = &lds[(kh * WP + (w + 1)) * CINP];
                    dst[0] = src[0]; dst[1] = src[1]; dst[2] = src[2];
                }
            }
        }
        __syncthreads();
        if (dok && tx < WW) {
            #pragma unroll
            for (int kh = 0; kh < 3; ++kh) {
                #pragma unroll
                for (int kw = 0; kw < 3; ++kw) {
                    const float* lrow = &lds[(kh * WP + tx + kw) * CINP];
                    const float* wrow = &wgt[(((kd * 3 + kh) * 3 + kw) * 3) * COUT + c0];
                    #pragma unroll
                    for (int ci = 0; ci < 3; ++ci) {
                        float s = lrow[ci];
                        float4 wa = ld4(wrow + ci * COUT);
                        float4 wb = ld4(wrow + ci * COUT + 4);
                        fma4(acc0, s, wa);
                        fma4(acc1, s, wb);
                    }
                }
            }
        }
    }
    if (tx < WW) {
        float4 ba = ld4(bias + c0), bb = ld4(bias + c0 + 4);
        unsigned short o[8];
        o[0] = f2bf(fmaxf(0.f, acc0.x + ba.x));
        o[1] = f2bf(fmaxf(0.f, acc0.y + ba.y));
        o[2] = f2bf(fmaxf(0.f, acc0.z + ba.z));
        o[3] = f2bf(fmaxf(0.f, acc0.w + ba.w));
        o[4] = f2bf(fmaxf(0.f, acc1.x + bb.x));
        o[5] = f2bf(fmaxf(0.f, acc1.y + bb.y));
        o[6] = f2bf(fmaxf(0.f, acc1.z + bb.z));
        o[7] = f2bf(fmaxf(0.f, acc1.w + bb.w));
        size_t ob = ((((size_t)n * DD + d) * HH + h) * WW + tx) * COUT + c0;
        *(short8v*)&out[ob] = *(short8v*)o;
    }
}

// ---------------------------------------------------------------------------
// bf16 MFMA implicit-GEMM conv3d, round-11 revision:
//  - Wave computes MW x NW output tiles (register blocking): each B-load
//    feeds MW MFMAs (was 1), each A-read feeds NW. Accumulation order per
//    tile unchanged -> bitwise-identical to round-10 output.
//  - Zero-init folded into staging (full padded ROWS x WP region written
//    with value-or-zero); one barrier instead of two.
// Constraint: (MTILES/MW)*(NTILES/NW) == 4 (waves).
// ---------------------------------------------------------------------------
template<int CIN, int COUT, int H, int W, int HROWS, int MW, int NW>
__global__ __launch_bounds__(256)
void convmf_k(const unsigned short* __restrict__ act,
              const unsigned short* __restrict__ pk,
              const float* __restrict__ bias,
              unsigned short* __restrict__ out)
{
    constexpr int CPT = CIN / 32;           // k-chunks per tap
    constexpr int CHUNKS = 27 * CPT;
    constexpr int KH = HROWS + 2;           // h-rows staged per kd slice
    constexpr int ROWS = 3 * KH;
    constexpr int WP = W + 2;
    constexpr int CINP = CIN + 8;
    constexpr int TPH = (W + 15) / 16;      // 16-wide m-tiles per h-row
    constexpr int MTILES = HROWS * TPH;
    constexpr int NTILES = COUT / 16;
    constexpr int MGROUPS = MTILES / MW;
    constexpr int LDSE = ROWS * WP * CINP;
    static_assert(MTILES % MW == 0 && NTILES % NW == 0, "tile divisibility");
    static_assert(MGROUPS * (NTILES / NW) == 4, "4-wave coverage");
    __shared__ __align__(16) short sh[LDSE + 512];   // +512 slack for dead-lane reads

    const int HB = H / HROWS;
    const int blk = blockIdx.x;
    const int hblk = blk % HB;
    const int d = (blk / HB) % DD;
    const int bn = blk / (HB * DD);
    const int h0 = hblk * HROWS;
    const int tid = threadIdx.x;
    const int lane = tid & 63;
    const int wave = tid >> 6;
    const int l15 = lane & 15;
    const int l4 = lane >> 4;

    // staging over the FULL padded region: value-or-zero (no separate zero pass)
    constexpr int C8 = CIN / 8;
    constexpr int V8R = WP * C8;            // 16B vectors per padded row
    for (int i = tid; i < ROWS * V8R; i += 256) {
        int r = i / V8R;
        int q = i - r * V8R;
        int wp_ = q / C8;
        int co = (q - wp_ * C8) * 8;
        int kd = r / KH, khh = r - kd * KH;
        int dp = d + kd - 1, hp = h0 + khh - 1;
        int w = wp_ - 1;
        short8v v = short8v{0, 0, 0, 0, 0, 0, 0, 0};
        if (dp >= 0 && dp < DD && hp >= 0 && hp < H && w >= 0 && w < W)
            v = *(const short8v*)&act[((((size_t)bn * DD + dp) * H + hp) * W + w) * CIN + co];
        *(short8v*)&sh[(r * WP + wp_) * CINP + co] = v;
    }
    __syncthreads();

    const int mg = wave % MGROUPS;
    const int ng = wave / MGROUPS;

    f32x4 acc[MW][NW];
    #pragma unroll
    for (int mi = 0; mi < MW; ++mi)
        #pragma unroll
        for (int ni = 0; ni < NW; ++ni)
            acc[mi][ni] = f32x4{0.f, 0.f, 0.f, 0.f};

    const short8v* bp = (const short8v*)pk;
    #pragma unroll 1
    for (int tap = 0; tap < 27; ++tap) {
        const int kd = tap / 9;
        const int rm = tap - kd * 9;
        const int kh = rm / 3;
        const int kw = rm - kh * 3;
        int abase[MW];
        #pragma unroll
        for (int mi = 0; mi < MW; ++mi) {
            const int mt = mg * MW + mi;
            const int row = kd * KH + kh + mt / TPH;
            const int wp = (mt % TPH) * 16 + l15 + kw;
            abase[mi] = (row * WP + wp) * CINP + l4 * 8;
        }
        #pragma unroll
        for (int cp = 0; cp < CPT; ++cp) {
            const int chunk = tap * CPT + cp;
            short8v a[MW], b[NW];
            #pragma unroll
            for (int mi = 0; mi < MW; ++mi)
                a[mi] = *(const short8v*)&sh[abase[mi] + cp * 32];
            #pragma unroll
            for (int ni = 0; ni < NW; ++ni)
                b[ni] = bp[((size_t)(ng * NW + ni) * CHUNKS + chunk) * 64 + lane];
            #pragma unroll
            for (int mi = 0; mi < MW; ++mi)
                #pragma unroll
                for (int ni = 0; ni < NW; ++ni)
                    acc[mi][ni] = __builtin_amdgcn_mfma_f32_16x16x32_bf16(a[mi], b[ni], acc[mi][ni], 0, 0, 0);
        }
    }

    #pragma unroll
    for (int mi = 0; mi < MW; ++mi) {
        const int mt = mg * MW + mi;
        const int hout = h0 + mt / TPH;
        const int wbase = (mt % TPH) * 16 + l4 * 4;
        #pragma unroll
        for (int ni = 0; ni < NW; ++ni) {
            const int cout = (ng * NW + ni) * 16 + l15;
            const float bi = bias[cout];
            #pragma unroll
            for (int r = 0; r < 4; ++r) {
                const int w = wbase + r;
                if (w < W) {
                    float v = fmaxf(0.f, acc[mi][ni][r] + bi);
                    out[((((size_t)bn * DD + d) * H + hout) * W + w) * COUT + cout] = f2bf(v);
                }
            }
        }
    }
}

// ---------------------------------------------------------------------------
// MaxPool (1,2,2) valid, bf16 (unchanged).
// ---------------------------------------------------------------------------
template<int C, int HO, int WO>
__global__ __launch_bounds__(256)
void poolb_k(const unsigned short* __restrict__ in, unsigned short* __restrict__ out,
             int total8, size_t obase)
{
    constexpr int C8 = C / 8;
    for (int idx = blockIdx.x * 256 + threadIdx.x; idx < total8; idx += gridDim.x * 256) {
        int c8 = idx % C8;
        int t = idx / C8;
        int wo = t % WO; t /= WO;
        int ho = t % HO; t /= HO;            // t = nd
        size_t base = (((size_t)t * (2 * HO) + 2 * ho) * (2 * WO) + 2 * wo) * C + c8 * 8;
        short8v a = *(const short8v*)&in[base];
        short8v b = *(const short8v*)&in[base + C];
        short8v c = *(const short8v*)&in[base + (size_t)(2 * WO) * C];
        short8v e = *(const short8v*)&in[base + (size_t)(2 * WO) * C + C];
        unsigned short o[8];
        #pragma unroll
        for (int j = 0; j < 8; ++j) {
            unsigned short av = (unsigned short)a[j], bv = (unsigned short)b[j];
            unsigned short cv = (unsigned short)c[j], ev = (unsigned short)e[j];
            unsigned short m1 = av > bv ? av : bv;
            unsigned short m2 = cv > ev ? cv : ev;
            o[j] = m1 > m2 ? m1 : m2;
        }
        *(short8v*)&out[obase + (size_t)idx * 8] = *(short8v*)o;
    }
}

// ---------------------------------------------------------------------------
// GlobalAveragePooling3D (unchanged).
// ---------------------------------------------------------------------------
__global__ __launch_bounds__(1024)
void gapb_k(const unsigned short* __restrict__ in, float* __restrict__ outf)
{
    __shared__ float part[8][128];
    const int n = blockIdx.x;
    const int c = threadIdx.x;
    const int dy = threadIdx.y;
    float s = 0.f;
    const unsigned short* p = &in[((size_t)n * 1568 + dy * 196) * 128 + c];
    #pragma unroll 4
    for (int i = 0; i < 196; ++i) s += bf2f(p[(size_t)i * 128]);
    part[dy][c] = s;
    __syncthreads();
    if (dy == 0) {
        float t = 0.f;
        #pragma unroll
        for (int k = 0; k < 8; ++k) t += part[k][c];
        outf[n * 128 + c] = t * (1.f / 1568.f);
    }
}

// ---------------------------------------------------------------------------
// Layer-1 input projection (parallel, unchanged from round 10).
// ---------------------------------------------------------------------------
__global__ __launch_bounds__(192)
void xp1_k(const float* __restrict__ feats, const float* __restrict__ wx,
           const float* __restrict__ gb, float* __restrict__ xp1)
{
    __shared__ float xrow[128];
    const int tb = blockIdx.x;           // t*2 + b
    const int b = tb & 1, t = tb >> 1;
    const int j = threadIdx.x;
    if (j < 128) xrow[j] = feats[(b * 13 + t) * 128 + j];
    __syncthreads();
    float s = gb[j];
    #pragma unroll 16
    for (int k = 0; k < 128; ++k) s = fmaf(xrow[k], wx[k * 192 + j], s);
    xp1[tb * 192 + j] = s;
}

// ---------------------------------------------------------------------------
// GRU scan (3 layers) + head, single block 384 (unchanged from round 10,
// verified: dropped from 500us to below top-5).
// ---------------------------------------------------------------------------
__global__ __launch_bounds__(384)
void gru2_k(const float* __restrict__ xp1,
            const float* __restrict__ g1_wh, const float* __restrict__ g1_b,
            const float* __restrict__ g2_wx, const float* __restrict__ g2_wh, const float* __restrict__ g2_b,
            const float* __restrict__ g3_wx, const float* __restrict__ g3_wh, const float* __restrict__ g3_b,
            const float* __restrict__ d1_w, const float* __restrict__ d1_b,
            const float* __restrict__ d2_w, const float* __restrict__ d2_b,
            const float* __restrict__ thr_w, const float* __restrict__ thr_b,
            const float* __restrict__ tori_w, const float* __restrict__ tori_b,
            float* __restrict__ out)
{
    __shared__ float xp[13 * 2 * 192];          // 19,968 B
    __shared__ float seq[26 * 64];              //  6,656 B
    __shared__ unsigned short wbuf[64 * 192];   // 24,576 B (bf16 weights)
    __shared__ float hbuf[2 * 64];
    __shared__ float rec[2 * 192];
    __shared__ float gbr[192];
    __shared__ float tmp[2 * 64];
    __shared__ float hd2[2 * 32];
    __shared__ float red[4];
    __shared__ float tl[4];
    const int tid = threadIdx.x;
    const int jj = tid % 192;
    const int bb = tid / 192;

    for (int i = tid; i < 13 * 2 * 192; i += 384) xp[i] = xp1[i];

    const float* WHs[3] = {g1_wh, g2_wh, g3_wh};
    const float* WXs[3] = {nullptr, g2_wx, g3_wx};
    const float* GBs[3] = {g1_b, g2_b, g3_b};

    for (int layer = 0; layer < 3; ++layer) {
        const float* gb = GBs[layer];
        if (layer > 0) {
            const float* wx = WXs[layer];
            for (int i = tid; i < 64 * 192; i += 384) wbuf[i] = f2bf(wx[i]);
            __syncthreads();
            const float bi = gb[jj];
            for (int t = 0; t < 13; ++t) {
                const float* xr = &seq[(bb * 13 + t) * 64];
                float s = bi;
                #pragma unroll 8
                for (int k = 0; k < 64; ++k) s = fmaf(xr[k], bf2f(wbuf[k * 192 + jj]), s);
                xp[(t * 2 + bb) * 192 + jj] = s;
            }
            __syncthreads();
        }
        const float* wh = WHs[layer];
        for (int i = tid; i < 64 * 192; i += 384) wbuf[i] = f2bf(wh[i]);
        if (tid < 192) gbr[tid] = gb[192 + tid];
        if (tid < 128) hbuf[tid] = 0.f;
        __syncthreads();
        for (int t = 0; t < 13; ++t) {
            {
                const float* hr = &hbuf[bb * 64];
                float s = gbr[jj];
                #pragma unroll 8
                for (int k = 0; k < 64; ++k) s = fmaf(hr[k], bf2f(wbuf[k * 192 + jj]), s);
                rec[tid] = s;
            }
            __syncthreads();
            if (tid < 128) {
                int b = tid / 64, u = tid % 64;
                const float* xpt = &xp[(t * 2 + b) * 192];
                const float* rc = &rec[b * 192];
                float z = sigmoidf(xpt[u] + rc[u]);
                float r = sigmoidf(xpt[64 + u] + rc[64 + u]);
                float hh = tanhf(xpt[128 + u] + r * rc[128 + u]);
                float hn = z * hbuf[b * 64 + u] + (1.f - z) * hh;
                hbuf[b * 64 + u] = hn;
                seq[(b * 13 + t) * 64 + u] = hn;
            }
            __syncthreads();
        }
    }

    if (tid < 128) {
        int b = tid / 64, u = tid % 64;
        float s = d1_b[u];
        for (int k = 0; k < 64; ++k) s = fmaf(hbuf[b * 64 + k], d1_w[k * 64 + u], s);
        tmp[b * 64 + u] = fmaxf(s, 0.f);
    }
    __syncthreads();
    if (tid < 64) {
        int b = tid / 32, u = tid % 32;
        float s = d2_b[u];
        for (int k = 0; k < 64; ++k) s = fmaf(tmp[b * 64 + k], d2_w[k * 32 + u], s);
        hd2[b * 32 + u] = fmaxf(s, 0.f);
    }
    __syncthreads();
    if (tid < 128) {
        int b = tid / 64, u = tid % 64;
        float s = thr_b[u];
        for (int k = 0; k < 32; ++k) s = fmaf(hd2[b * 32 + k], thr_w[k * 64 + u], s);
        tmp[b * 64 + u] = s;
    }
    if (tid >= 128 && tid < 132) {
        int i = tid - 128;
        int b = i >> 1, u = i & 1;
        float s = tori_b[u];
        for (int k = 0; k < 32; ++k) s = fmaf(hd2[b * 32 + k], tori_w[k * 2 + u], s);
        tl[i] = s;
    }
    __syncthreads();
    if (tid < 2) {
        float m = -1e30f;
        for (int u = 0; u < 64; ++u) m = fmaxf(m, tmp[tid * 64 + u]);
        float s = 0.f;
        for (int u = 0; u < 64; ++u) s += expf(tmp[tid * 64 + u] - m);
        red[tid * 2] = m;
        red[tid * 2 + 1] = s;
    }
    __syncthreads();
    if (tid < 128) {
        int b = tid >> 6;
        out[tid] = expf(tmp[tid] - red[b * 2]) / red[b * 2 + 1];
    }
    if (tid >= 128 && tid < 130) {
        int b = tid - 128;
        float a = tl[b * 2], c = tl[b * 2 + 1];
        float m = fmaxf(a, c);
        float e0 = expf(a - m), e1 = expf(c - m);
        float inv = 1.f / (e0 + e1);
        out[128 + b * 2 + 0] = e0 * inv;
        out[128 + b * 2 + 1] = e1 * inv;
    }
}

// ---------------------------------------------------------------------------
extern "C" void kernel_launch(void* const* d_in, const int* in_sizes, int n_in,
                              void* d_out, int out_size, void* d_ws, size_t ws_size,
                              hipStream_t stream) {
    const float* inputs = (const float*)d_in[0];
    const float* c11_k = (const float*)d_in[1];  const float* c11_b = (const float*)d_in[2];
    const float* c12_k = (const float*)d_in[3];  const float* c12_b = (const float*)d_in[4];
    const float* c21_k = (const float*)d_in[5];  const float* c21_b = (const float*)d_in[6];
    const float* c22_k = (const float*)d_in[7];  const float* c22_b = (const float*)d_in[8];
    const float* c31_k = (const float*)d_in[9];  const float* c31_b = (const float*)d_in[10];
    const float* c32_k = (const float*)d_in[11]; const float* c32_b = (const float*)d_in[12];
    const float* g1_wx = (const float*)d_in[13]; const float* g1_wh = (const float*)d_in[14]; const float* g1_b = (const float*)d_in[15];
    const float* g2_wx = (const float*)d_in[16]; const float* g2_wh = (const float*)d_in[17]; const float* g2_b = (const float*)d_in[18];
    const float* g3_wx = (const float*)d_in[19]; const float* g3_wh = (const float*)d_in[20]; const float* g3_b = (const float*)d_in[21];
    const float* d1_w = (const float*)d_in[22];  const float* d1_b = (const float*)d_in[23];
    const float* d2_w = (const float*)d_in[24];  const float* d2_b = (const float*)d_in[25];
    const float* thr_w = (const float*)d_in[26]; const float* thr_b = (const float*)d_in[27];
    const float* tori_w = (const float*)d_in[28]; const float* tori_b = (const float*)d_in[29];

    typedef unsigned short u16;
    char* base = (char*)d_ws;
    // packed weights (bf16 elems): c12 27648, c21 55296, c22 110592, c31 221184, c32 442368
    u16* pk12 = (u16*)base;
    u16* pk21 = pk12 + 27648;
    u16* pk22 = pk21 + 55296;
    u16* pk31 = pk22 + 110592;
    u16* pk32 = pk31 + 221184;                 // end 1,714,176 B
    float* feats = (float*)(base + 1714176);   // 13,312 B
    float* xp1   = (float*)(base + 1727488);   // 19,968 B
    u16* p1 = (u16*)(base + 1747456);          // 10,436,608 B
    u16* hA = (u16*)(base + 12184064);         // 20,873,216 B
    u16* hB = (u16*)(base + 33057280);         // 20,873,216 B; total 53,930,496 B
    float* out = (float*)d_out;

    // pack weights (graph-safe, recomputed every launch)
    pack_w_k<<<108, 256, 0, stream>>>(c12_k, pk12, 27, 32, 27648);
    pack_w_k<<<216, 256, 0, stream>>>(c21_k, pk21, 27, 64, 55296);
    pack_w_k<<<432, 256, 0, stream>>>(c22_k, pk22, 54, 64, 110592);
    pack_w_k<<<864, 256, 0, stream>>>(c31_k, pk31, 54, 128, 221184);
    pack_w_k<<<1728, 256, 0, stream>>>(c32_k, pk32, 108, 128, 442368);

    // stage 1 in two batch halves (keeps peak ws at 53.9 MB)
    for (int b = 0; b < 2; ++b) {
        conv_c11_k<<<13 * 8 * 56, dim3(64, 4), 0, stream>>>(inputs, c11_k, c11_b, hA, b);
        convmf_k<32, 32, 56, 56, 1, 2, 1><<<13 * 8 * 56, 256, 0, stream>>>(hA, pk12, c12_b, hB);
        poolb_k<32, 28, 28><<<1274, 256, 0, stream>>>(hB, p1, 13 * 8 * 28 * 28 * 4, (size_t)b * 2609152);
    }
    // stages 2-3 full batch (26 sequences)
    convmf_k<32, 64, 28, 28, 2, 2, 2><<<26 * 8 * 14, 256, 0, stream>>>(p1, pk21, c21_b, hA);
    convmf_k<64, 64, 28, 28, 1, 2, 1><<<26 * 8 * 28, 256, 0, stream>>>(hA, pk22, c22_b, hB);
    poolb_k<64, 14, 14><<<1274, 256, 0, stream>>>(hB, p1, 26 * 8 * 14 * 14 * 8, 0);
    convmf_k<64, 128, 14, 14, 2, 2, 2><<<26 * 8 * 7, 256, 0, stream>>>(p1, pk31, c31_b, hA);
    convmf_k<128, 128, 14, 14, 2, 2, 2><<<26 * 8 * 7, 256, 0, stream>>>(hA, pk32, c32_b, hB);
    gapb_k<<<26, dim3(128, 8), 0, stream>>>(hB, feats);

    // GRU: parallel layer-1 projection, then LDS-staged scan
    xp1_k<<<26, 192, 0, stream>>>(feats, g1_wx, g1_b, xp1);
    gru2_k<<<1, 384, 0, stream>>>(xp1,
        g1_wh, g1_b, g2_wx, g2_wh, g2_b, g3_wx, g3_wh, g3_b,
        d1_w, d1_b, d2_w, d2_b, thr_w, thr_b, tori_w, tori_b, out);
}

// Round 14
// 642.627 us; speedup vs baseline: 15.7788x; 1.2115x over previous
//
#include <hip/hip_runtime.h>
#include <math.h>

#define DD 8

typedef __attribute__((ext_vector_type(8))) short short8v;
typedef __attribute__((ext_vector_type(4))) float f32x4;

__device__ __forceinline__ float4 ld4(const float* p) {
    return *reinterpret_cast<const float4*>(p);
}
__device__ __forceinline__ void st4(float* p, float4 v) {
    *reinterpret_cast<float4*>(p) = v;
}
__device__ __forceinline__ void fma4(float4& a, float s, float4 w) {
    a.x = fmaf(s, w.x, a.x);
    a.y = fmaf(s, w.y, a.y);
    a.z = fmaf(s, w.z, a.z);
    a.w = fmaf(s, w.w, a.w);
}
__device__ __forceinline__ float sigmoidf(float x) { return 1.f / (1.f + expf(-x)); }

__device__ __forceinline__ float bf2f(unsigned short u) {
    union { unsigned int i; float f; } v; v.i = ((unsigned int)u) << 16; return v.f;
}
__device__ __forceinline__ unsigned short f2bf(float f) {
    union { float f; unsigned int i; } v; v.f = f;
    unsigned int r = v.i + 0x7FFFu + ((v.i >> 16) & 1u);
    return (unsigned short)(r >> 16);
}

// ---------------------------------------------------------------------------
// Weight pre-pack: wgt (K=27*CIN, COUT) fp32 -> bf16 fragments (unchanged).
// ---------------------------------------------------------------------------
__global__ __launch_bounds__(256)
void pack_w_k(const float* __restrict__ wgt, unsigned short* __restrict__ pk,
              int chunks, int cout_n, int total)
{
    for (int id = blockIdx.x * 256 + threadIdx.x; id < total; id += gridDim.x * 256) {
        int j = id & 7;
        int l = (id >> 3) & 63;
        int rest = id >> 9;
        int chunk = rest % chunks;
        int nt = rest / chunks;
        int k = chunk * 32 + ((l >> 4) << 3) + j;
        int cout = nt * 16 + (l & 15);
        pk[id] = f2bf(wgt[(size_t)k * cout_n + cout]);
    }
}

// ---------------------------------------------------------------------------
// First conv fp32 direct (CIN=3), round-13 rewrite:
//  - 4 output h-rows per block (grid/4): 4 independent acc chains -> ILP.
//  - Weights staged once in LDS (flat layout identical to input tensor).
//  - Single barrier; validity via zero-filled input slab (fmaf(0,w,a)=a
//    exactly -> bitwise-identical to prior rounds).
//  - slab CINP=3: lane stride 3 coprime with 32 banks -> conflict-free.
// grid = 13*8*14, block (64,4). b = batch index.
// ---------------------------------------------------------------------------
__global__ __launch_bounds__(256)
void conv_c11_k(const float* __restrict__ in, const float* __restrict__ wgt,
                const float* __restrict__ bias, unsigned short* __restrict__ out, int b)
{
    constexpr int HH = 56, WW = 56, WP = 58, COUT = 32, HR = 4, SR = HR + 2;
    __shared__ float wlds[27 * 3 * 32];      // [tap][ci][cout] = 10368 B
    __shared__ float slab[3 * SR * WP * 3];  // [frame][row][wp][ci] = 12528 B
    const int blk = blockIdx.x;
    const int hg = blk % 14;
    const int d = (blk / 14) % DD;
    const int n = blk / (14 * DD);           // window index = start frame t
    const int h0 = hg * HR;
    const int tx = threadIdx.x, ty = threadIdx.y;
    const int tid = ty * 64 + tx;

    // stage weights: wgt flat ((kd*3+kh)*3+kw)*3+ci)*32+cout == (tap*3+ci)*32+cout
    for (int i = tid; i < 27 * 3 * 32; i += 256) wlds[i] = wgt[i];
    // stage zero-filled input slab (3 frames x 6 rows x 58 wp x 3 ci)
    for (int i = tid; i < 3 * SR * WP * 3; i += 256) {
        int ci = i % 3;
        int rest = i / 3;
        int wp = rest % WP; rest /= WP;
        int r = rest % SR;
        int f = rest / SR;                   // kd
        int d2 = d + f - 1;
        int h2 = h0 + r - 1;
        int w = wp - 1;
        float v = 0.f;
        if (d2 >= 0 && d2 < DD && h2 >= 0 && h2 < HH && w >= 0 && w < WW) {
            int frame = b * 20 + n + d2;
            v = in[(((size_t)frame * HH + h2) * WW + w) * 3 + ci];
        }
        slab[i] = v;
    }
    __syncthreads();

    const int c0 = ty * 8;
    if (tx < WW) {
        float4 a0[HR], a1[HR];
        #pragma unroll
        for (int hh = 0; hh < HR; ++hh) {
            a0[hh] = float4{0, 0, 0, 0};
            a1[hh] = float4{0, 0, 0, 0};
        }
        #pragma unroll
        for (int f = 0; f < 3; ++f) {
            #pragma unroll
            for (int kh = 0; kh < 3; ++kh) {
                #pragma unroll
                for (int kw = 0; kw < 3; ++kw) {
                    const float* wr = &wlds[((f * 9 + kh * 3 + kw) * 3) * 32 + c0];
                    float4 w0a = ld4(wr);            float4 w0b = ld4(wr + 4);
                    float4 w1a = ld4(wr + 32);       float4 w1b = ld4(wr + 36);
                    float4 w2a = ld4(wr + 64);       float4 w2b = ld4(wr + 68);
                    #pragma unroll
                    for (int hh = 0; hh < HR; ++hh) {
                        const float* lr = &slab[((f * SR + hh + kh) * WP + tx + kw) * 3];
                        float s0 = lr[0], s1 = lr[1], s2 = lr[2];
                        fma4(a0[hh], s0, w0a); fma4(a1[hh], s0, w0b);
                        fma4(a0[hh], s1, w1a); fma4(a1[hh], s1, w1b);
                        fma4(a0[hh], s2, w2a); fma4(a1[hh], s2, w2b);
                    }
                }
            }
        }
        float4 ba = ld4(bias + c0), bb = ld4(bias + c0 + 4);
        #pragma unroll
        for (int hh = 0; hh < HR; ++hh) {
            unsigned short o[8];
            o[0] = f2bf(fmaxf(0.f, a0[hh].x + ba.x));
            o[1] = f2bf(fmaxf(0.f, a0[hh].y + ba.y));
            o[2] = f2bf(fmaxf(0.f, a0[hh].z + ba.z));
            o[3] = f2bf(fmaxf(0.f, a0[hh].w + ba.w));
            o[4] = f2bf(fmaxf(0.f, a1[hh].x + bb.x));
            o[5] = f2bf(fmaxf(0.f, a1[hh].y + bb.y));
            o[6] = f2bf(fmaxf(0.f, a1[hh].z + bb.z));
            o[7] = f2bf(fmaxf(0.f, a1[hh].w + bb.w));
            size_t ob = ((((size_t)n * DD + d) * HH + (h0 + hh)) * WW + tx) * COUT + c0;
            *(short8v*)&out[ob] = *(short8v*)o;
        }
    }
}

// ---------------------------------------------------------------------------
// bf16 MFMA implicit-GEMM conv3d (round-11 revision, verified round 12).
// ---------------------------------------------------------------------------
template<int CIN, int COUT, int H, int W, int HROWS, int MW, int NW>
__global__ __launch_bounds__(256)
void convmf_k(const unsigned short* __restrict__ act,
              const unsigned short* __restrict__ pk,
              const float* __restrict__ bias,
              unsigned short* __restrict__ out)
{
    constexpr int CPT = CIN / 32;           // k-chunks per tap
    constexpr int CHUNKS = 27 * CPT;
    constexpr int KH = HROWS + 2;           // h-rows staged per kd slice
    constexpr int ROWS = 3 * KH;
    constexpr int WP = W + 2;
    constexpr int CINP = CIN + 8;
    constexpr int TPH = (W + 15) / 16;      // 16-wide m-tiles per h-row
    constexpr int MTILES = HROWS * TPH;
    constexpr int NTILES = COUT / 16;
    constexpr int MGROUPS = MTILES / MW;
    constexpr int LDSE = ROWS * WP * CINP;
    static_assert(MTILES % MW == 0 && NTILES % NW == 0, "tile divisibility");
    static_assert(MGROUPS * (NTILES / NW) == 4, "4-wave coverage");
    __shared__ __align__(16) short sh[LDSE + 512];   // +512 slack for dead-lane reads

    const int HB = H / HROWS;
    const int blk = blockIdx.x;
    const int hblk = blk % HB;
    const int d = (blk / HB) % DD;
    const int bn = blk / (HB * DD);
    const int h0 = hblk * HROWS;
    const int tid = threadIdx.x;
    const int lane = tid & 63;
    const int wave = tid >> 6;
    const int l15 = lane & 15;
    const int l4 = lane >> 4;

    // staging over the FULL padded region: value-or-zero (no separate zero pass)
    constexpr int C8 = CIN / 8;
    constexpr int V8R = WP * C8;            // 16B vectors per padded row
    for (int i = tid; i < ROWS * V8R; i += 256) {
        int r = i / V8R;
        int q = i - r * V8R;
        int wp_ = q / C8;
        int co = (q - wp_ * C8) * 8;
        int kd = r / KH, khh = r - kd * KH;
        int dp = d + kd - 1, hp = h0 + khh - 1;
        int w = wp_ - 1;
        short8v v = short8v{0, 0, 0, 0, 0, 0, 0, 0};
        if (dp >= 0 && dp < DD && hp >= 0 && hp < H && w >= 0 && w < W)
            v = *(const short8v*)&act[((((size_t)bn * DD + dp) * H + hp) * W + w) * CIN + co];
        *(short8v*)&sh[(r * WP + wp_) * CINP + co] = v;
    }
    __syncthreads();

    const int mg = wave % MGROUPS;
    const int ng = wave / MGROUPS;

    f32x4 acc[MW][NW];
    #pragma unroll
    for (int mi = 0; mi < MW; ++mi)
        #pragma unroll
        for (int ni = 0; ni < NW; ++ni)
            acc[mi][ni] = f32x4{0.f, 0.f, 0.f, 0.f};

    const short8v* bp = (const short8v*)pk;
    #pragma unroll 1
    for (int tap = 0; tap < 27; ++tap) {
        const int kd = tap / 9;
        const int rm = tap - kd * 9;
        const int kh = rm / 3;
        const int kw = rm - kh * 3;
        int abase[MW];
        #pragma unroll
        for (int mi = 0; mi < MW; ++mi) {
            const int mt = mg * MW + mi;
            const int row = kd * KH + kh + mt / TPH;
            const int wp = (mt % TPH) * 16 + l15 + kw;
            abase[mi] = (row * WP + wp) * CINP + l4 * 8;
        }
        #pragma unroll
        for (int cp = 0; cp < CPT; ++cp) {
            const int chunk = tap * CPT + cp;
            short8v a[MW], b[NW];
            #pragma unroll
            for (int mi = 0; mi < MW; ++mi)
                a[mi] = *(const short8v*)&sh[abase[mi] + cp * 32];
            #pragma unroll
            for (int ni = 0; ni < NW; ++ni)
                b[ni] = bp[((size_t)(ng * NW + ni) * CHUNKS + chunk) * 64 + lane];
            #pragma unroll
            for (int mi = 0; mi < MW; ++mi)
                #pragma unroll
                for (int ni = 0; ni < NW; ++ni)
                    acc[mi][ni] = __builtin_amdgcn_mfma_f32_16x16x32_bf16(a[mi], b[ni], acc[mi][ni], 0, 0, 0);
        }
    }

    #pragma unroll
    for (int mi = 0; mi < MW; ++mi) {
        const int mt = mg * MW + mi;
        const int hout = h0 + mt / TPH;
        const int wbase = (mt % TPH) * 16 + l4 * 4;
        #pragma unroll
        for (int ni = 0; ni < NW; ++ni) {
            const int cout = (ng * NW + ni) * 16 + l15;
            const float bi = bias[cout];
            #pragma unroll
            for (int r = 0; r < 4; ++r) {
                const int w = wbase + r;
                if (w < W) {
                    float v = fmaxf(0.f, acc[mi][ni][r] + bi);
                    out[((((size_t)bn * DD + d) * H + hout) * W + w) * COUT + cout] = f2bf(v);
                }
            }
        }
    }
}

// ---------------------------------------------------------------------------
// MaxPool (1,2,2) valid, bf16 (unchanged).
// ---------------------------------------------------------------------------
template<int C, int HO, int WO>
__global__ __launch_bounds__(256)
void poolb_k(const unsigned short* __restrict__ in, unsigned short* __restrict__ out,
             int total8, size_t obase)
{
    constexpr int C8 = C / 8;
    for (int idx = blockIdx.x * 256 + threadIdx.x; idx < total8; idx += gridDim.x * 256) {
        int c8 = idx % C8;
        int t = idx / C8;
        int wo = t % WO; t /= WO;
        int ho = t % HO; t /= HO;            // t = nd
        size_t base = (((size_t)t * (2 * HO) + 2 * ho) * (2 * WO) + 2 * wo) * C + c8 * 8;
        short8v a = *(const short8v*)&in[base];
        short8v b = *(const short8v*)&in[base + C];
        short8v c = *(const short8v*)&in[base + (size_t)(2 * WO) * C];
        short8v e = *(const short8v*)&in[base + (size_t)(2 * WO) * C + C];
        unsigned short o[8];
        #pragma unroll
        for (int j = 0; j < 8; ++j) {
            unsigned short av = (unsigned short)a[j], bv = (unsigned short)b[j];
            unsigned short cv = (unsigned short)c[j], ev = (unsigned short)e[j];
            unsigned short m1 = av > bv ? av : bv;
            unsigned short m2 = cv > ev ? cv : ev;
            o[j] = m1 > m2 ? m1 : m2;
        }
        *(short8v*)&out[obase + (size_t)idx * 8] = *(short8v*)o;
    }
}

// ---------------------------------------------------------------------------
// GlobalAveragePooling3D (unchanged).
// ---------------------------------------------------------------------------
__global__ __launch_bounds__(1024)
void gapb_k(const unsigned short* __restrict__ in, float* __restrict__ outf)
{
    __shared__ float part[8][128];
    const int n = blockIdx.x;
    const int c = threadIdx.x;
    const int dy = threadIdx.y;
    float s = 0.f;
    const unsigned short* p = &in[((size_t)n * 1568 + dy * 196) * 128 + c];
    #pragma unroll 4
    for (int i = 0; i < 196; ++i) s += bf2f(p[(size_t)i * 128]);
    part[dy][c] = s;
    __syncthreads();
    if (dy == 0) {
        float t = 0.f;
        #pragma unroll
        for (int k = 0; k < 8; ++k) t += part[k][c];
        outf[n * 128 + c] = t * (1.f / 1568.f);
    }
}

// ---------------------------------------------------------------------------
// Layer-1 input projection (parallel, unchanged).
// ---------------------------------------------------------------------------
__global__ __launch_bounds__(192)
void xp1_k(const float* __restrict__ feats, const float* __restrict__ wx,
           const float* __restrict__ gb, float* __restrict__ xp1)
{
    __shared__ float xrow[128];
    const int tb = blockIdx.x;           // t*2 + b
    const int b = tb & 1, t = tb >> 1;
    const int j = threadIdx.x;
    if (j < 128) xrow[j] = feats[(b * 13 + t) * 128 + j];
    __syncthreads();
    float s = gb[j];
    #pragma unroll 16
    for (int k = 0; k < 128; ++k) s = fmaf(xrow[k], wx[k * 192 + j], s);
    xp1[tb * 192 + j] = s;
}

// ---------------------------------------------------------------------------
// GRU scan (3 layers) + head, single block 384 (unchanged, verified r10).
// ---------------------------------------------------------------------------
__global__ __launch_bounds__(384)
void gru2_k(const float* __restrict__ xp1,
            const float* __restrict__ g1_wh, const float* __restrict__ g1_b,
            const float* __restrict__ g2_wx, const float* __restrict__ g2_wh, const float* __restrict__ g2_b,
            const float* __restrict__ g3_wx, const float* __restrict__ g3_wh, const float* __restrict__ g3_b,
            const float* __restrict__ d1_w, const float* __restrict__ d1_b,
            const float* __restrict__ d2_w, const float* __restrict__ d2_b,
            const float* __restrict__ thr_w, const float* __restrict__ thr_b,
            const float* __restrict__ tori_w, const float* __restrict__ tori_b,
            float* __restrict__ out)
{
    __shared__ float xp[13 * 2 * 192];          // 19,968 B
    __shared__ float seq[26 * 64];              //  6,656 B
    __shared__ unsigned short wbuf[64 * 192];   // 24,576 B (bf16 weights)
    __shared__ float hbuf[2 * 64];
    __shared__ float rec[2 * 192];
    __shared__ float gbr[192];
    __shared__ float tmp[2 * 64];
    __shared__ float hd2[2 * 32];
    __shared__ float red[4];
    __shared__ float tl[4];
    const int tid = threadIdx.x;
    const int jj = tid % 192;
    const int bb = tid / 192;

    for (int i = tid; i < 13 * 2 * 192; i += 384) xp[i] = xp1[i];

    const float* WHs[3] = {g1_wh, g2_wh, g3_wh};
    const float* WXs[3] = {nullptr, g2_wx, g3_wx};
    const float* GBs[3] = {g1_b, g2_b, g3_b};

    for (int layer = 0; layer < 3; ++layer) {
        const float* gb = GBs[layer];
        if (layer > 0) {
            const float* wx = WXs[layer];
            for (int i = tid; i < 64 * 192; i += 384) wbuf[i] = f2bf(wx[i]);
            __syncthreads();
            const float bi = gb[jj];
            for (int t = 0; t < 13; ++t) {
                const float* xr = &seq[(bb * 13 + t) * 64];
                float s = bi;
                #pragma unroll 8
                for (int k = 0; k < 64; ++k) s = fmaf(xr[k], bf2f(wbuf[k * 192 + jj]), s);
                xp[(t * 2 + bb) * 192 + jj] = s;
            }
            __syncthreads();
        }
        const float* wh = WHs[layer];
        for (int i = tid; i < 64 * 192; i += 384) wbuf[i] = f2bf(wh[i]);
        if (tid < 192) gbr[tid] = gb[192 + tid];
        if (tid < 128) hbuf[tid] = 0.f;
        __syncthreads();
        for (int t = 0; t < 13; ++t) {
            {
                const float* hr = &hbuf[bb * 64];
                float s = gbr[jj];
                #pragma unroll 8
                for (int k = 0; k < 64; ++k) s = fmaf(hr[k], bf2f(wbuf[k * 192 + jj]), s);
                rec[tid] = s;
            }
            __syncthreads();
            if (tid < 128) {
                int b = tid / 64, u = tid % 64;
                const float* xpt = &xp[(t * 2 + b) * 192];
                const float* rc = &rec[b * 192];
                float z = sigmoidf(xpt[u] + rc[u]);
                float r = sigmoidf(xpt[64 + u] + rc[64 + u]);
                float hh = tanhf(xpt[128 + u] + r * rc[128 + u]);
                float hn = z * hbuf[b * 64 + u] + (1.f - z) * hh;
                hbuf[b * 64 + u] = hn;
                seq[(b * 13 + t) * 64 + u] = hn;
            }
            __syncthreads();
        }
    }

    if (tid < 128) {
        int b = tid / 64, u = tid % 64;
        float s = d1_b[u];
        for (int k = 0; k < 64; ++k) s = fmaf(hbuf[b * 64 + k], d1_w[k * 64 + u], s);
        tmp[b * 64 + u] = fmaxf(s, 0.f);
    }
    __syncthreads();
    if (tid < 64) {
        int b = tid / 32, u = tid % 32;
        float s = d2_b[u];
        for (int k = 0; k < 64; ++k) s = fmaf(tmp[b * 64 + k], d2_w[k * 32 + u], s);
        hd2[b * 32 + u] = fmaxf(s, 0.f);
    }
    __syncthreads();
    if (tid < 128) {
        int b = tid / 64, u = tid % 64;
        float s = thr_b[u];
        for (int k = 0; k < 32; ++k) s = fmaf(hd2[b * 32 + k], thr_w[k * 64 + u], s);
        tmp[b * 64 + u] = s;
    }
    if (tid >= 128 && tid < 132) {
        int i = tid - 128;
        int b = i >> 1, u = i & 1;
        float s = tori_b[u];
        for (int k = 0; k < 32; ++k) s = fmaf(hd2[b * 32 + k], tori_w[k * 2 + u], s);
        tl[i] = s;
    }
    __syncthreads();
    if (tid < 2) {
        float m = -1e30f;
        for (int u = 0; u < 64; ++u) m = fmaxf(m, tmp[tid * 64 + u]);
        float s = 0.f;
        for (int u = 0; u < 64; ++u) s += expf(tmp[tid * 64 + u] - m);
        red[tid * 2] = m;
        red[tid * 2 + 1] = s;
    }
    __syncthreads();
    if (tid < 128) {
        int b = tid >> 6;
        out[tid] = expf(tmp[tid] - red[b * 2]) / red[b * 2 + 1];
    }
    if (tid >= 128 && tid < 130) {
        int b = tid - 128;
        float a = tl[b * 2], c = tl[b * 2 + 1];
        float m = fmaxf(a, c);
        float e0 = expf(a - m), e1 = expf(c - m);
        float inv = 1.f / (e0 + e1);
        out[128 + b * 2 + 0] = e0 * inv;
        out[128 + b * 2 + 1] = e1 * inv;
    }
}

// ---------------------------------------------------------------------------
extern "C" void kernel_launch(void* const* d_in, const int* in_sizes, int n_in,
                              void* d_out, int out_size, void* d_ws, size_t ws_size,
                              hipStream_t stream) {
    const float* inputs = (const float*)d_in[0];
    const float* c11_k = (const float*)d_in[1];  const float* c11_b = (const float*)d_in[2];
    const float* c12_k = (const float*)d_in[3];  const float* c12_b = (const float*)d_in[4];
    const float* c21_k = (const float*)d_in[5];  const float* c21_b = (const float*)d_in[6];
    const float* c22_k = (const float*)d_in[7];  const float* c22_b = (const float*)d_in[8];
    const float* c31_k = (const float*)d_in[9];  const float* c31_b = (const float*)d_in[10];
    const float* c32_k = (const float*)d_in[11]; const float* c32_b = (const float*)d_in[12];
    const float* g1_wx = (const float*)d_in[13]; const float* g1_wh = (const float*)d_in[14]; const float* g1_b = (const float*)d_in[15];
    const float* g2_wx = (const float*)d_in[16]; const float* g2_wh = (const float*)d_in[17]; const float* g2_b = (const float*)d_in[18];
    const float* g3_wx = (const float*)d_in[19]; const float* g3_wh = (const float*)d_in[20]; const float* g3_b = (const float*)d_in[21];
    const float* d1_w = (const float*)d_in[22];  const float* d1_b = (const float*)d_in[23];
    const float* d2_w = (const float*)d_in[24];  const float* d2_b = (const float*)d_in[25];
    const float* thr_w = (const float*)d_in[26]; const float* thr_b = (const float*)d_in[27];
    const float* tori_w = (const float*)d_in[28]; const float* tori_b = (const float*)d_in[29];

    typedef unsigned short u16;
    char* base = (char*)d_ws;
    // packed weights (bf16 elems): c12 27648, c21 55296, c22 110592, c31 221184, c32 442368
    u16* pk12 = (u16*)base;
    u16* pk21 = pk12 + 27648;
    u16* pk22 = pk21 + 55296;
    u16* pk31 = pk22 + 110592;
    u16* pk32 = pk31 + 221184;                 // end 1,714,176 B
    float* feats = (float*)(base + 1714176);   // 13,312 B
    float* xp1   = (float*)(base + 1727488);   // 19,968 B
    u16* p1 = (u16*)(base + 1747456);          // 10,436,608 B
    u16* hA = (u16*)(base + 12184064);         // 20,873,216 B
    u16* hB = (u16*)(base + 33057280);         // 20,873,216 B; total 53,930,496 B
    float* out = (float*)d_out;

    // pack weights (graph-safe, recomputed every launch)
    pack_w_k<<<108, 256, 0, stream>>>(c12_k, pk12, 27, 32, 27648);
    pack_w_k<<<216, 256, 0, stream>>>(c21_k, pk21, 27, 64, 55296);
    pack_w_k<<<432, 256, 0, stream>>>(c22_k, pk22, 54, 64, 110592);
    pack_w_k<<<864, 256, 0, stream>>>(c31_k, pk31, 54, 128, 221184);
    pack_w_k<<<1728, 256, 0, stream>>>(c32_k, pk32, 108, 128, 442368);

    // stage 1 in two batch halves (keeps peak ws at 53.9 MB)
    for (int b = 0; b < 2; ++b) {
        conv_c11_k<<<13 * 8 * 14, dim3(64, 4), 0, stream>>>(inputs, c11_k, c11_b, hA, b);
        convmf_k<32, 32, 56, 56, 1, 2, 1><<<13 * 8 * 56, 256, 0, stream>>>(hA, pk12, c12_b, hB);
        poolb_k<32, 28, 28><<<1274, 256, 0, stream>>>(hB, p1, 13 * 8 * 28 * 28 * 4, (size_t)b * 2609152);
    }
    // stages 2-3 full batch (26 sequences)
    convmf_k<32, 64, 28, 28, 2, 2, 2><<<26 * 8 * 14, 256, 0, stream>>>(p1, pk21, c21_b, hA);
    convmf_k<64, 64, 28, 28, 1, 2, 1><<<26 * 8 * 28, 256, 0, stream>>>(hA, pk22, c22_b, hB);
    poolb_k<64, 14, 14><<<1274, 256, 0, stream>>>(hB, p1, 26 * 8 * 14 * 14 * 8, 0);
    convmf_k<64, 128, 14, 14, 2, 2, 2><<<26 * 8 * 7, 256, 0, stream>>>(p1, pk31, c31_b, hA);
    convmf_k<128, 128, 14, 14, 2, 2, 2><<<26 * 8 * 7, 256, 0, stream>>>(hA, pk32, c32_b, hB);
    gapb_k<<<26, dim3(128, 8), 0, stream>>>(hB, feats);

    // GRU: parallel layer-1 projection, then LDS-staged scan
    xp1_k<<<26, 192, 0, stream>>>(feats, g1_wx, g1_b, xp1);
    gru2_k<<<1, 384, 0, stream>>>(xp1,
        g1_wh, g1_b, g2_wx, g2_wh, g2_b, g3_wx, g3_wh, g3_b,
        d1_w, d1_b, d2_w, d2_b, thr_w, thr_b, tori_w, tori_b, out);
}

// Round 15
// 594.107 us; speedup vs baseline: 17.0674x; 1.0817x over previous
//
#include <hip/hip_runtime.h>
#include <math.h>

#define DD 8

typedef __attribute__((ext_vector_type(8))) short short8v;
typedef __attribute__((ext_vector_type(4))) float f32x4;

__device__ __forceinline__ float4 ld4(const float* p) {
    return *reinterpret_cast<const float4*>(p);
}
__device__ __forceinline__ void st4(float* p, float4 v) {
    *reinterpret_cast<float4*>(p) = v;
}
__device__ __forceinline__ void fma4(float4& a, float s, float4 w) {
    a.x = fmaf(s, w.x, a.x);
    a.y = fmaf(s, w.y, a.y);
    a.z = fmaf(s, w.z, a.z);
    a.w = fmaf(s, w.w, a.w);
}
__device__ __forceinline__ float sigmoidf(float x) { return 1.f / (1.f + expf(-x)); }

__device__ __forceinline__ float bf2f(unsigned short u) {
    union { unsigned int i; float f; } v; v.i = ((unsigned int)u) << 16; return v.f;
}
__device__ __forceinline__ unsigned short f2bf(float f) {
    union { float f; unsigned int i; } v; v.f = f;
    unsigned int r = v.i + 0x7FFFu + ((v.i >> 16) & 1u);
    return (unsigned short)(r >> 16);
}

// ---------------------------------------------------------------------------
// Fused weight pre-pack for all 5 conv layers (1 launch instead of 5).
// Same per-element math as before: pk[((nt*chunks+chunk)*64+l)*8+j] =
//   bf16(wgt[k*coutn + cout]), k = chunk*32+(l>>4)*8+j, cout = nt*16+(l&15).
// Segment boundaries (elems): 27648 / 82944 / 193536 / 414720 / 857088.
// ---------------------------------------------------------------------------
__global__ __launch_bounds__(256)
void pack_all_k(const float* __restrict__ w12, const float* __restrict__ w21,
                const float* __restrict__ w22, const float* __restrict__ w31,
                const float* __restrict__ w32, unsigned short* __restrict__ pk)
{
    for (int id = blockIdx.x * 256 + threadIdx.x; id < 857088; id += gridDim.x * 256) {
        const float* wgt; int chunks, coutn, local;
        if (id < 27648)       { wgt = w12; chunks = 27;  coutn = 32;  local = id; }
        else if (id < 82944)  { wgt = w21; chunks = 27;  coutn = 64;  local = id - 27648; }
        else if (id < 193536) { wgt = w22; chunks = 54;  coutn = 64;  local = id - 82944; }
        else if (id < 414720) { wgt = w31; chunks = 54;  coutn = 128; local = id - 193536; }
        else                  { wgt = w32; chunks = 108; coutn = 128; local = id - 414720; }
        int j = local & 7;
        int l = (local >> 3) & 63;
        int rest = local >> 9;
        int chunk = rest % chunks;
        int nt = rest / chunks;
        int k = chunk * 32 + ((l >> 4) << 3) + j;
        int cout = nt * 16 + (l & 15);
        pk[id] = f2bf(wgt[(size_t)k * coutn + cout]);
    }
}

// ---------------------------------------------------------------------------
// First conv fp32 direct (CIN=3) — verified round 14, unchanged.
// grid = 13*8*14, block (64,4).
// ---------------------------------------------------------------------------
__global__ __launch_bounds__(256)
void conv_c11_k(const float* __restrict__ in, const float* __restrict__ wgt,
                const float* __restrict__ bias, unsigned short* __restrict__ out, int b)
{
    constexpr int HH = 56, WW = 56, WP = 58, COUT = 32, HR = 4, SR = HR + 2;
    __shared__ float wlds[27 * 3 * 32];      // [tap][ci][cout] = 10368 B
    __shared__ float slab[3 * SR * WP * 3];  // [frame][row][wp][ci] = 12528 B
    const int blk = blockIdx.x;
    const int hg = blk % 14;
    const int d = (blk / 14) % DD;
    const int n = blk / (14 * DD);           // window index = start frame t
    const int h0 = hg * HR;
    const int tx = threadIdx.x, ty = threadIdx.y;
    const int tid = ty * 64 + tx;

    for (int i = tid; i < 27 * 3 * 32; i += 256) wlds[i] = wgt[i];
    for (int i = tid; i < 3 * SR * WP * 3; i += 256) {
        int ci = i % 3;
        int rest = i / 3;
        int wp = rest % WP; rest /= WP;
        int r = rest % SR;
        int f = rest / SR;                   // kd
        int d2 = d + f - 1;
        int h2 = h0 + r - 1;
        int w = wp - 1;
        float v = 0.f;
        if (d2 >= 0 && d2 < DD && h2 >= 0 && h2 < HH && w >= 0 && w < WW) {
            int frame = b * 20 + n + d2;
            v = in[(((size_t)frame * HH + h2) * WW + w) * 3 + ci];
        }
        slab[i] = v;
    }
    __syncthreads();

    const int c0 = ty * 8;
    if (tx < WW) {
        float4 a0[HR], a1[HR];
        #pragma unroll
        for (int hh = 0; hh < HR; ++hh) {
            a0[hh] = float4{0, 0, 0, 0};
            a1[hh] = float4{0, 0, 0, 0};
        }
        #pragma unroll
        for (int f = 0; f < 3; ++f) {
            #pragma unroll
            for (int kh = 0; kh < 3; ++kh) {
                #pragma unroll
                for (int kw = 0; kw < 3; ++kw) {
                    const float* wr = &wlds[((f * 9 + kh * 3 + kw) * 3) * 32 + c0];
                    float4 w0a = ld4(wr);            float4 w0b = ld4(wr + 4);
                    float4 w1a = ld4(wr + 32);       float4 w1b = ld4(wr + 36);
                    float4 w2a = ld4(wr + 64);       float4 w2b = ld4(wr + 68);
                    #pragma unroll
                    for (int hh = 0; hh < HR; ++hh) {
                        const float* lr = &slab[((f * SR + hh + kh) * WP + tx + kw) * 3];
                        float s0 = lr[0], s1 = lr[1], s2 = lr[2];
                        fma4(a0[hh], s0, w0a); fma4(a1[hh], s0, w0b);
                        fma4(a0[hh], s1, w1a); fma4(a1[hh], s1, w1b);
                        fma4(a0[hh], s2, w2a); fma4(a1[hh], s2, w2b);
                    }
                }
            }
        }
        float4 ba = ld4(bias + c0), bb = ld4(bias + c0 + 4);
        #pragma unroll
        for (int hh = 0; hh < HR; ++hh) {
            unsigned short o[8];
            o[0] = f2bf(fmaxf(0.f, a0[hh].x + ba.x));
            o[1] = f2bf(fmaxf(0.f, a0[hh].y + ba.y));
            o[2] = f2bf(fmaxf(0.f, a0[hh].z + ba.z));
            o[3] = f2bf(fmaxf(0.f, a0[hh].w + ba.w));
            o[4] = f2bf(fmaxf(0.f, a1[hh].x + bb.x));
            o[5] = f2bf(fmaxf(0.f, a1[hh].y + bb.y));
            o[6] = f2bf(fmaxf(0.f, a1[hh].z + bb.z));
            o[7] = f2bf(fmaxf(0.f, a1[hh].w + bb.w));
            size_t ob = ((((size_t)n * DD + d) * HH + (h0 + hh)) * WW + tx) * COUT + c0;
            *(short8v*)&out[ob] = *(short8v*)o;
        }
    }
}

// ---------------------------------------------------------------------------
// bf16 MFMA implicit-GEMM conv3d (MW x NW register blocking, verified r12/r14).
// Round-15 delta: tap-loop unroll 1 -> 3 (deeper B-load pipelining).
// ---------------------------------------------------------------------------
template<int CIN, int COUT, int H, int W, int HROWS, int MW, int NW>
__global__ __launch_bounds__(256)
void convmf_k(const unsigned short* __restrict__ act,
              const unsigned short* __restrict__ pk,
              const float* __restrict__ bias,
              unsigned short* __restrict__ out)
{
    constexpr int CPT = CIN / 32;           // k-chunks per tap
    constexpr int CHUNKS = 27 * CPT;
    constexpr int KH = HROWS + 2;           // h-rows staged per kd slice
    constexpr int ROWS = 3 * KH;
    constexpr int WP = W + 2;
    constexpr int CINP = CIN + 8;
    constexpr int TPH = (W + 15) / 16;      // 16-wide m-tiles per h-row
    constexpr int MTILES = HROWS * TPH;
    constexpr int NTILES = COUT / 16;
    constexpr int MGROUPS = MTILES / MW;
    constexpr int LDSE = ROWS * WP * CINP;
    static_assert(MTILES % MW == 0 && NTILES % NW == 0, "tile divisibility");
    static_assert(MGROUPS * (NTILES / NW) == 4, "4-wave coverage");
    __shared__ __align__(16) short sh[LDSE + 512];   // +512 slack for dead-lane reads

    const int HB = H / HROWS;
    const int blk = blockIdx.x;
    const int hblk = blk % HB;
    const int d = (blk / HB) % DD;
    const int bn = blk / (HB * DD);
    const int h0 = hblk * HROWS;
    const int tid = threadIdx.x;
    const int lane = tid & 63;
    const int wave = tid >> 6;
    const int l15 = lane & 15;
    const int l4 = lane >> 4;

    constexpr int C8 = CIN / 8;
    constexpr int V8R = WP * C8;            // 16B vectors per padded row
    for (int i = tid; i < ROWS * V8R; i += 256) {
        int r = i / V8R;
        int q = i - r * V8R;
        int wp_ = q / C8;
        int co = (q - wp_ * C8) * 8;
        int kd = r / KH, khh = r - kd * KH;
        int dp = d + kd - 1, hp = h0 + khh - 1;
        int w = wp_ - 1;
        short8v v = short8v{0, 0, 0, 0, 0, 0, 0, 0};
        if (dp >= 0 && dp < DD && hp >= 0 && hp < H && w >= 0 && w < W)
            v = *(const short8v*)&act[((((size_t)bn * DD + dp) * H + hp) * W + w) * CIN + co];
        *(short8v*)&sh[(r * WP + wp_) * CINP + co] = v;
    }
    __syncthreads();

    const int mg = wave % MGROUPS;
    const int ng = wave / MGROUPS;

    f32x4 acc[MW][NW];
    #pragma unroll
    for (int mi = 0; mi < MW; ++mi)
        #pragma unroll
        for (int ni = 0; ni < NW; ++ni)
            acc[mi][ni] = f32x4{0.f, 0.f, 0.f, 0.f};

    const short8v* bp = (const short8v*)pk;
    #pragma unroll 3
    for (int tap = 0; tap < 27; ++tap) {
        const int kd = tap / 9;
        const int rm = tap - kd * 9;
        const int kh = rm / 3;
        const int kw = rm - kh * 3;
        int abase[MW];
        #pragma unroll
        for (int mi = 0; mi < MW; ++mi) {
            const int mt = mg * MW + mi;
            const int row = kd * KH + kh + mt / TPH;
            const int wp = (mt % TPH) * 16 + l15 + kw;
            abase[mi] = (row * WP + wp) * CINP + l4 * 8;
        }
        #pragma unroll
        for (int cp = 0; cp < CPT; ++cp) {
            const int chunk = tap * CPT + cp;
            short8v a[MW], b[NW];
            #pragma unroll
            for (int mi = 0; mi < MW; ++mi)
                a[mi] = *(const short8v*)&sh[abase[mi] + cp * 32];
            #pragma unroll
            for (int ni = 0; ni < NW; ++ni)
                b[ni] = bp[((size_t)(ng * NW + ni) * CHUNKS + chunk) * 64 + lane];
            #pragma unroll
            for (int mi = 0; mi < MW; ++mi)
                #pragma unroll
                for (int ni = 0; ni < NW; ++ni)
                    acc[mi][ni] = __builtin_amdgcn_mfma_f32_16x16x32_bf16(a[mi], b[ni], acc[mi][ni], 0, 0, 0);
        }
    }

    #pragma unroll
    for (int mi = 0; mi < MW; ++mi) {
        const int mt = mg * MW + mi;
        const int hout = h0 + mt / TPH;
        const int wbase = (mt % TPH) * 16 + l4 * 4;
        #pragma unroll
        for (int ni = 0; ni < NW; ++ni) {
            const int cout = (ng * NW + ni) * 16 + l15;
            const float bi = bias[cout];
            #pragma unroll
            for (int r = 0; r < 4; ++r) {
                const int w = wbase + r;
                if (w < W) {
                    float v = fmaxf(0.f, acc[mi][ni][r] + bi);
                    out[((((size_t)bn * DD + d) * H + hout) * W + w) * COUT + cout] = f2bf(v);
                }
            }
        }
    }
}

// ---------------------------------------------------------------------------
// MaxPool (1,2,2) valid, bf16 (unchanged).
// ---------------------------------------------------------------------------
template<int C, int HO, int WO>
__global__ __launch_bounds__(256)
void poolb_k(const unsigned short* __restrict__ in, unsigned short* __restrict__ out,
             int total8, size_t obase)
{
    constexpr int C8 = C / 8;
    for (int idx = blockIdx.x * 256 + threadIdx.x; idx < total8; idx += gridDim.x * 256) {
        int c8 = idx % C8;
        int t = idx / C8;
        int wo = t % WO; t /= WO;
        int ho = t % HO; t /= HO;            // t = nd
        size_t base = (((size_t)t * (2 * HO) + 2 * ho) * (2 * WO) + 2 * wo) * C + c8 * 8;
        short8v a = *(const short8v*)&in[base];
        short8v b = *(const short8v*)&in[base + C];
        short8v c = *(const short8v*)&in[base + (size_t)(2 * WO) * C];
        short8v e = *(const short8v*)&in[base + (size_t)(2 * WO) * C + C];
        unsigned short o[8];
        #pragma unroll
        for (int j = 0; j < 8; ++j) {
            unsigned short av = (unsigned short)a[j], bv = (unsigned short)b[j];
            unsigned short cv = (unsigned short)c[j], ev = (unsigned short)e[j];
            unsigned short m1 = av > bv ? av : bv;
            unsigned short m2 = cv > ev ? cv : ev;
            o[j] = m1 > m2 ? m1 : m2;
        }
        *(short8v*)&out[obase + (size_t)idx * 8] = *(short8v*)o;
    }
}

// ---------------------------------------------------------------------------
// GlobalAveragePooling3D (unchanged).
// ---------------------------------------------------------------------------
__global__ __launch_bounds__(1024)
void gapb_k(const unsigned short* __restrict__ in, float* __restrict__ outf)
{
    __shared__ float part[8][128];
    const int n = blockIdx.x;
    const int c = threadIdx.x;
    const int dy = threadIdx.y;
    float s = 0.f;
    const unsigned short* p = &in[((size_t)n * 1568 + dy * 196) * 128 + c];
    #pragma unroll 4
    for (int i = 0; i < 196; ++i) s += bf2f(p[(size_t)i * 128]);
    part[dy][c] = s;
    __syncthreads();
    if (dy == 0) {
        float t = 0.f;
        #pragma unroll
        for (int k = 0; k < 8; ++k) t += part[k][c];
        outf[n * 128 + c] = t * (1.f / 1568.f);
    }
}

// ---------------------------------------------------------------------------
// Layer-1 input projection (parallel, unchanged).
// ---------------------------------------------------------------------------
__global__ __launch_bounds__(192)
void xp1_k(const float* __restrict__ feats, const float* __restrict__ wx,
           const float* __restrict__ gb, float* __restrict__ xp1)
{
    __shared__ float xrow[128];
    const int tb = blockIdx.x;           // t*2 + b
    const int b = tb & 1, t = tb >> 1;
    const int j = threadIdx.x;
    if (j < 128) xrow[j] = feats[(b * 13 + t) * 128 + j];
    __syncthreads();
    float s = gb[j];
    #pragma unroll 16
    for (int k = 0; k < 128; ++k) s = fmaf(xrow[k], wx[k * 192 + j], s);
    xp1[tb * 192 + j] = s;
}

// ---------------------------------------------------------------------------
// GRU scan (3 layers) + head, single block 384.
// Round-15 delta: rec/xp dot products split into 4 partial accumulators
// (breaks the serial FMA chain 4-way; compiler hoists 4 LDS reads).
// ---------------------------------------------------------------------------
__global__ __launch_bounds__(384)
void gru2_k(const float* __restrict__ xp1,
            const float* __restrict__ g1_wh, const float* __restrict__ g1_b,
            const float* __restrict__ g2_wx, const float* __restrict__ g2_wh, const float* __restrict__ g2_b,
            const float* __restrict__ g3_wx, const float* __restrict__ g3_wh, const float* __restrict__ g3_b,
            const float* __restrict__ d1_w, const float* __restrict__ d1_b,
            const float* __restrict__ d2_w, const float* __restrict__ d2_b,
            const float* __restrict__ thr_w, const float* __restrict__ thr_b,
            const float* __restrict__ tori_w, const float* __restrict__ tori_b,
            float* __restrict__ out)
{
    __shared__ float xp[13 * 2 * 192];          // 19,968 B
    __shared__ float seq[26 * 64];              //  6,656 B
    __shared__ unsigned short wbuf[64 * 192];   // 24,576 B (bf16 weights)
    __shared__ float hbuf[2 * 64];
    __shared__ float rec[2 * 192];
    __shared__ float gbr[192];
    __shared__ float tmp[2 * 64];
    __shared__ float hd2[2 * 32];
    __shared__ float red[4];
    __shared__ float tl[4];
    const int tid = threadIdx.x;
    const int jj = tid % 192;
    const int bb = tid / 192;

    for (int i = tid; i < 13 * 2 * 192; i += 384) xp[i] = xp1[i];

    const float* WHs[3] = {g1_wh, g2_wh, g3_wh};
    const float* WXs[3] = {nullptr, g2_wx, g3_wx};
    const float* GBs[3] = {g1_b, g2_b, g3_b};

    for (int layer = 0; layer < 3; ++layer) {
        const float* gb = GBs[layer];
        if (layer > 0) {
            const float* wx = WXs[layer];
            for (int i = tid; i < 64 * 192; i += 384) wbuf[i] = f2bf(wx[i]);
            __syncthreads();
            const float bi = gb[jj];
            for (int t = 0; t < 13; ++t) {
                const float* xr = &seq[(bb * 13 + t) * 64];
                float s0 = 0.f, s1 = 0.f, s2 = 0.f, s3 = 0.f;
                #pragma unroll 8
                for (int k = 0; k < 64; k += 4) {
                    s0 = fmaf(xr[k + 0], bf2f(wbuf[(k + 0) * 192 + jj]), s0);
                    s1 = fmaf(xr[k + 1], bf2f(wbuf[(k + 1) * 192 + jj]), s1);
                    s2 = fmaf(xr[k + 2], bf2f(wbuf[(k + 2) * 192 + jj]), s2);
                    s3 = fmaf(xr[k + 3], bf2f(wbuf[(k + 3) * 192 + jj]), s3);
                }
                xp[(t * 2 + bb) * 192 + jj] = bi + ((s0 + s1) + (s2 + s3));
            }
            __syncthreads();
        }
        const float* wh = WHs[layer];
        for (int i = tid; i < 64 * 192; i += 384) wbuf[i] = f2bf(wh[i]);
        if (tid < 192) gbr[tid] = gb[192 + tid];
        if (tid < 128) hbuf[tid] = 0.f;
        __syncthreads();
        for (int t = 0; t < 13; ++t) {
            {
                const float* hr = &hbuf[bb * 64];
                float s0 = 0.f, s1 = 0.f, s2 = 0.f, s3 = 0.f;
                #pragma unroll 8
                for (int k = 0; k < 64; k += 4) {
                    s0 = fmaf(hr[k + 0], bf2f(wbuf[(k + 0) * 192 + jj]), s0);
                    s1 = fmaf(hr[k + 1], bf2f(wbuf[(k + 1) * 192 + jj]), s1);
                    s2 = fmaf(hr[k + 2], bf2f(wbuf[(k + 2) * 192 + jj]), s2);
                    s3 = fmaf(hr[k + 3], bf2f(wbuf[(k + 3) * 192 + jj]), s3);
                }
                rec[tid] = gbr[jj] + ((s0 + s1) + (s2 + s3));
            }
            __syncthreads();
            if (tid < 128) {
                int b = tid / 64, u = tid % 64;
                const float* xpt = &xp[(t * 2 + b) * 192];
                const float* rc = &rec[b * 192];
                float z = sigmoidf(xpt[u] + rc[u]);
                float r = sigmoidf(xpt[64 + u] + rc[64 + u]);
                float hh = tanhf(xpt[128 + u] + r * rc[128 + u]);
                float hn = z * hbuf[b * 64 + u] + (1.f - z) * hh;
                hbuf[b * 64 + u] = hn;
                seq[(b * 13 + t) * 64 + u] = hn;
            }
            __syncthreads();
        }
    }

    if (tid < 128) {
        int b = tid / 64, u = tid % 64;
        float s = d1_b[u];
        for (int k = 0; k < 64; ++k) s = fmaf(hbuf[b * 64 + k], d1_w[k * 64 + u], s);
        tmp[b * 64 + u] = fmaxf(s, 0.f);
    }
    __syncthreads();
    if (tid < 64) {
        int b = tid / 32, u = tid % 32;
        float s = d2_b[u];
        for (int k = 0; k < 64; ++k) s = fmaf(tmp[b * 64 + k], d2_w[k * 32 + u], s);
        hd2[b * 32 + u] = fmaxf(s, 0.f);
    }
    __syncthreads();
    if (tid < 128) {
        int b = tid / 64, u = tid % 64;
        float s = thr_b[u];
        for (int k = 0; k < 32; ++k) s = fmaf(hd2[b * 32 + k], thr_w[k * 64 + u], s);
        tmp[b * 64 + u] = s;
    }
    if (tid >= 128 && tid < 132) {
        int i = tid - 128;
        int b = i >> 1, u = i & 1;
        float s = tori_b[u];
        for (int k = 0; k < 32; ++k) s = fmaf(hd2[b * 32 + k], tori_w[k * 2 + u], s);
        tl[i] = s;
    }
    __syncthreads();
    if (tid < 2) {
        float m = -1e30f;
        for (int u = 0; u < 64; ++u) m = fmaxf(m, tmp[tid * 64 + u]);
        float s = 0.f;
        for (int u = 0; u < 64; ++u) s += expf(tmp[tid * 64 + u] - m);
        red[tid * 2] = m;
        red[tid * 2 + 1] = s;
    }
    __syncthreads();
    if (tid < 128) {
        int b = tid >> 6;
        out[tid] = expf(tmp[tid] - red[b * 2]) / red[b * 2 + 1];
    }
    if (tid >= 128 && tid < 130) {
        int b = tid - 128;
        float a = tl[b * 2], c = tl[b * 2 + 1];
        float m = fmaxf(a, c);
        float e0 = expf(a - m), e1 = expf(c - m);
        float inv = 1.f / (e0 + e1);
        out[128 + b * 2 + 0] = e0 * inv;
        out[128 + b * 2 + 1] = e1 * inv;
    }
}

// ---------------------------------------------------------------------------
extern "C" void kernel_launch(void* const* d_in, const int* in_sizes, int n_in,
                              void* d_out, int out_size, void* d_ws, size_t ws_size,
                              hipStream_t stream) {
    const float* inputs = (const float*)d_in[0];
    const float* c11_k = (const float*)d_in[1];  const float* c11_b = (const float*)d_in[2];
    const float* c12_k = (const float*)d_in[3];  const float* c12_b = (const float*)d_in[4];
    const float* c21_k = (const float*)d_in[5];  const float* c21_b = (const float*)d_in[6];
    const float* c22_k = (const float*)d_in[7];  const float* c22_b = (const float*)d_in[8];
    const float* c31_k = (const float*)d_in[9];  const float* c31_b = (const float*)d_in[10];
    const float* c32_k = (const float*)d_in[11]; const float* c32_b = (const float*)d_in[12];
    const float* g1_wx = (const float*)d_in[13]; const float* g1_wh = (const float*)d_in[14]; const float* g1_b = (const float*)d_in[15];
    const float* g2_wx = (const float*)d_in[16]; const float* g2_wh = (const float*)d_in[17]; const float* g2_b = (const float*)d_in[18];
    const float* g3_wx = (const float*)d_in[19]; const float* g3_wh = (const float*)d_in[20]; const float* g3_b = (const float*)d_in[21];
    const float* d1_w = (const float*)d_in[22];  const float* d1_b = (const float*)d_in[23];
    const float* d2_w = (const float*)d_in[24];  const float* d2_b = (const float*)d_in[25];
    const float* thr_w = (const float*)d_in[26]; const float* thr_b = (const float*)d_in[27];
    const float* tori_w = (const float*)d_in[28]; const float* tori_b = (const float*)d_in[29];

    typedef unsigned short u16;
    char* base = (char*)d_ws;
    // packed weights, contiguous (bf16 elems): c12 @0, c21 @27648, c22 @82944,
    // c31 @193536, c32 @414720; end 857088 elems -> 1,714,176 B
    u16* pkall = (u16*)base;
    u16* pk12 = pkall;
    u16* pk21 = pkall + 27648;
    u16* pk22 = pkall + 82944;
    u16* pk31 = pkall + 193536;
    u16* pk32 = pkall + 414720;
    float* feats = (float*)(base + 1714176);   // 13,312 B
    float* xp1   = (float*)(base + 1727488);   // 19,968 B
    u16* p1 = (u16*)(base + 1747456);          // 10,436,608 B
    u16* hA = (u16*)(base + 12184064);         // 20,873,216 B
    u16* hB = (u16*)(base + 33057280);         // 20,873,216 B; total 53,930,496 B
    float* out = (float*)d_out;

    // pack all conv weights in one launch (graph-safe, recomputed every launch)
    pack_all_k<<<1674, 256, 0, stream>>>(c12_k, c21_k, c22_k, c31_k, c32_k, pkall);

    // stage 1 in two batch halves (keeps peak ws at 53.9 MB)
    for (int b = 0; b < 2; ++b) {
        conv_c11_k<<<13 * 8 * 14, dim3(64, 4), 0, stream>>>(inputs, c11_k, c11_b, hA, b);
        convmf_k<32, 32, 56, 56, 1, 2, 1><<<13 * 8 * 56, 256, 0, stream>>>(hA, pk12, c12_b, hB);
        poolb_k<32, 28, 28><<<1274, 256, 0, stream>>>(hB, p1, 13 * 8 * 28 * 28 * 4, (size_t)b * 2609152);
    }
    // stages 2-3 full batch (26 sequences)
    convmf_k<32, 64, 28, 28, 2, 2, 2><<<26 * 8 * 14, 256, 0, stream>>>(p1, pk21, c21_b, hA);
    convmf_k<64, 64, 28, 28, 1, 2, 1><<<26 * 8 * 28, 256, 0, stream>>>(hA, pk22, c22_b, hB);
    poolb_k<64, 14, 14><<<1274, 256, 0, stream>>>(hB, p1, 26 * 8 * 14 * 14 * 8, 0);
    convmf_k<64, 128, 14, 14, 2, 2, 2><<<26 * 8 * 7, 256, 0, stream>>>(p1, pk31, c31_b, hA);
    convmf_k<128, 128, 14, 14, 2, 2, 2><<<26 * 8 * 7, 256, 0, stream>>>(hA, pk32, c32_b, hB);
    gapb_k<<<26, dim3(128, 8), 0, stream>>>(hB, feats);

    // GRU: parallel layer-1 projection, then LDS-staged scan
    xp1_k<<<26, 192, 0, stream>>>(feats, g1_wx, g1_b, xp1);
    gru2_k<<<1, 384, 0, stream>>>(xp1,
        g1_wh, g1_b, g2_wx, g2_wh, g2_b, g3_wx, g3_wh, g3_b,
        d1_w, d1_b, d2_w, d2_b, thr_w, thr_b, tori_w, tori_b, out);
}

// Round 16
// 590.527 us; speedup vs baseline: 17.1709x; 1.0061x over previous
//
#include <hip/hip_runtime.h>
#include <math.h>

#define DD 8

typedef __attribute__((ext_vector_type(8))) short short8v;
typedef __attribute__((ext_vector_type(4))) float f32x4;

__device__ __forceinline__ float4 ld4(const float* p) {
    return *reinterpret_cast<const float4*>(p);
}
__device__ __forceinline__ void st4(float* p, float4 v) {
    *reinterpret_cast<float4*>(p) = v;
}
__device__ __forceinline__ void fma4(float4& a, float s, float4 w) {
    a.x = fmaf(s, w.x, a.x);
    a.y = fmaf(s, w.y, a.y);
    a.z = fmaf(s, w.z, a.z);
    a.w = fmaf(s, w.w, a.w);
}
__device__ __forceinline__ float sigmoidf(float x) { return 1.f / (1.f + expf(-x)); }

__device__ __forceinline__ float bf2f(unsigned short u) {
    union { unsigned int i; float f; } v; v.i = ((unsigned int)u) << 16; return v.f;
}
__device__ __forceinline__ unsigned short f2bf(float f) {
    union { float f; unsigned int i; } v; v.f = f;
    unsigned int r = v.i + 0x7FFFu + ((v.i >> 16) & 1u);
    return (unsigned short)(r >> 16);
}

// ---------------------------------------------------------------------------
// Fused weight pre-pack for all 5 conv layers (verified round 15).
// ---------------------------------------------------------------------------
__global__ __launch_bounds__(256)
void pack_all_k(const float* __restrict__ w12, const float* __restrict__ w21,
                const float* __restrict__ w22, const float* __restrict__ w31,
                const float* __restrict__ w32, unsigned short* __restrict__ pk)
{
    for (int id = blockIdx.x * 256 + threadIdx.x; id < 857088; id += gridDim.x * 256) {
        const float* wgt; int chunks, coutn, local;
        if (id < 27648)       { wgt = w12; chunks = 27;  coutn = 32;  local = id; }
        else if (id < 82944)  { wgt = w21; chunks = 27;  coutn = 64;  local = id - 27648; }
        else if (id < 193536) { wgt = w22; chunks = 54;  coutn = 64;  local = id - 82944; }
        else if (id < 414720) { wgt = w31; chunks = 54;  coutn = 128; local = id - 193536; }
        else                  { wgt = w32; chunks = 108; coutn = 128; local = id - 414720; }
        int j = local & 7;
        int l = (local >> 3) & 63;
        int rest = local >> 9;
        int chunk = rest % chunks;
        int nt = rest / chunks;
        int k = chunk * 32 + ((l >> 4) << 3) + j;
        int cout = nt * 16 + (l & 15);
        pk[id] = f2bf(wgt[(size_t)k * coutn + cout]);
    }
}

// ---------------------------------------------------------------------------
// First conv fp32 direct (CIN=3) — verified round 14, unchanged.
// grid = 13*8*14, block (64,4).
// ---------------------------------------------------------------------------
__global__ __launch_bounds__(256)
void conv_c11_k(const float* __restrict__ in, const float* __restrict__ wgt,
                const float* __restrict__ bias, unsigned short* __restrict__ out, int b)
{
    constexpr int HH = 56, WW = 56, WP = 58, COUT = 32, HR = 4, SR = HR + 2;
    __shared__ float wlds[27 * 3 * 32];      // [tap][ci][cout] = 10368 B
    __shared__ float slab[3 * SR * WP * 3];  // [frame][row][wp][ci] = 12528 B
    const int blk = blockIdx.x;
    const int hg = blk % 14;
    const int d = (blk / 14) % DD;
    const int n = blk / (14 * DD);           // window index = start frame t
    const int h0 = hg * HR;
    const int tx = threadIdx.x, ty = threadIdx.y;
    const int tid = ty * 64 + tx;

    for (int i = tid; i < 27 * 3 * 32; i += 256) wlds[i] = wgt[i];
    for (int i = tid; i < 3 * SR * WP * 3; i += 256) {
        int ci = i % 3;
        int rest = i / 3;
        int wp = rest % WP; rest /= WP;
        int r = rest % SR;
        int f = rest / SR;                   // kd
        int d2 = d + f - 1;
        int h2 = h0 + r - 1;
        int w = wp - 1;
        float v = 0.f;
        if (d2 >= 0 && d2 < DD && h2 >= 0 && h2 < HH && w >= 0 && w < WW) {
            int frame = b * 20 + n + d2;
            v = in[(((size_t)frame * HH + h2) * WW + w) * 3 + ci];
        }
        slab[i] = v;
    }
    __syncthreads();

    const int c0 = ty * 8;
    if (tx < WW) {
        float4 a0[HR], a1[HR];
        #pragma unroll
        for (int hh = 0; hh < HR; ++hh) {
            a0[hh] = float4{0, 0, 0, 0};
            a1[hh] = float4{0, 0, 0, 0};
        }
        #pragma unroll
        for (int f = 0; f < 3; ++f) {
            #pragma unroll
            for (int kh = 0; kh < 3; ++kh) {
                #pragma unroll
                for (int kw = 0; kw < 3; ++kw) {
                    const float* wr = &wlds[((f * 9 + kh * 3 + kw) * 3) * 32 + c0];
                    float4 w0a = ld4(wr);            float4 w0b = ld4(wr + 4);
                    float4 w1a = ld4(wr + 32);       float4 w1b = ld4(wr + 36);
                    float4 w2a = ld4(wr + 64);       float4 w2b = ld4(wr + 68);
                    #pragma unroll
                    for (int hh = 0; hh < HR; ++hh) {
                        const float* lr = &slab[((f * SR + hh + kh) * WP + tx + kw) * 3];
                        float s0 = lr[0], s1 = lr[1], s2 = lr[2];
                        fma4(a0[hh], s0, w0a); fma4(a1[hh], s0, w0b);
                        fma4(a0[hh], s1, w1a); fma4(a1[hh], s1, w1b);
                        fma4(a0[hh], s2, w2a); fma4(a1[hh], s2, w2b);
                    }
                }
            }
        }
        float4 ba = ld4(bias + c0), bb = ld4(bias + c0 + 4);
        #pragma unroll
        for (int hh = 0; hh < HR; ++hh) {
            unsigned short o[8];
            o[0] = f2bf(fmaxf(0.f, a0[hh].x + ba.x));
            o[1] = f2bf(fmaxf(0.f, a0[hh].y + ba.y));
            o[2] = f2bf(fmaxf(0.f, a0[hh].z + ba.z));
            o[3] = f2bf(fmaxf(0.f, a0[hh].w + ba.w));
            o[4] = f2bf(fmaxf(0.f, a1[hh].x + bb.x));
            o[5] = f2bf(fmaxf(0.f, a1[hh].y + bb.y));
            o[6] = f2bf(fmaxf(0.f, a1[hh].z + bb.z));
            o[7] = f2bf(fmaxf(0.f, a1[hh].w + bb.w));
            size_t ob = ((((size_t)n * DD + d) * HH + (h0 + hh)) * WW + tx) * COUT + c0;
            *(short8v*)&out[ob] = *(short8v*)o;
        }
    }
}

// ---------------------------------------------------------------------------
// bf16 MFMA implicit-GEMM conv3d (MW x NW blocking + tap unroll 3, verified r15).
// ---------------------------------------------------------------------------
template<int CIN, int COUT, int H, int W, int HROWS, int MW, int NW>
__global__ __launch_bounds__(256)
void convmf_k(const unsigned short* __restrict__ act,
              const unsigned short* __restrict__ pk,
              const float* __restrict__ bias,
              unsigned short* __restrict__ out)
{
    constexpr int CPT = CIN / 32;           // k-chunks per tap
    constexpr int CHUNKS = 27 * CPT;
    constexpr int KH = HROWS + 2;           // h-rows staged per kd slice
    constexpr int ROWS = 3 * KH;
    constexpr int WP = W + 2;
    constexpr int CINP = CIN + 8;
    constexpr int TPH = (W + 15) / 16;      // 16-wide m-tiles per h-row
    constexpr int MTILES = HROWS * TPH;
    constexpr int NTILES = COUT / 16;
    constexpr int MGROUPS = MTILES / MW;
    constexpr int LDSE = ROWS * WP * CINP;
    static_assert(MTILES % MW == 0 && NTILES % NW == 0, "tile divisibility");
    static_assert(MGROUPS * (NTILES / NW) == 4, "4-wave coverage");
    __shared__ __align__(16) short sh[LDSE + 512];   // +512 slack for dead-lane reads

    const int HB = H / HROWS;
    const int blk = blockIdx.x;
    const int hblk = blk % HB;
    const int d = (blk / HB) % DD;
    const int bn = blk / (HB * DD);
    const int h0 = hblk * HROWS;
    const int tid = threadIdx.x;
    const int lane = tid & 63;
    const int wave = tid >> 6;
    const int l15 = lane & 15;
    const int l4 = lane >> 4;

    constexpr int C8 = CIN / 8;
    constexpr int V8R = WP * C8;            // 16B vectors per padded row
    for (int i = tid; i < ROWS * V8R; i += 256) {
        int r = i / V8R;
        int q = i - r * V8R;
        int wp_ = q / C8;
        int co = (q - wp_ * C8) * 8;
        int kd = r / KH, khh = r - kd * KH;
        int dp = d + kd - 1, hp = h0 + khh - 1;
        int w = wp_ - 1;
        short8v v = short8v{0, 0, 0, 0, 0, 0, 0, 0};
        if (dp >= 0 && dp < DD && hp >= 0 && hp < H && w >= 0 && w < W)
            v = *(const short8v*)&act[((((size_t)bn * DD + dp) * H + hp) * W + w) * CIN + co];
        *(short8v*)&sh[(r * WP + wp_) * CINP + co] = v;
    }
    __syncthreads();

    const int mg = wave % MGROUPS;
    const int ng = wave / MGROUPS;

    f32x4 acc[MW][NW];
    #pragma unroll
    for (int mi = 0; mi < MW; ++mi)
        #pragma unroll
        for (int ni = 0; ni < NW; ++ni)
            acc[mi][ni] = f32x4{0.f, 0.f, 0.f, 0.f};

    const short8v* bp = (const short8v*)pk;
    #pragma unroll 3
    for (int tap = 0; tap < 27; ++tap) {
        const int kd = tap / 9;
        const int rm = tap - kd * 9;
        const int kh = rm / 3;
        const int kw = rm - kh * 3;
        int abase[MW];
        #pragma unroll
        for (int mi = 0; mi < MW; ++mi) {
            const int mt = mg * MW + mi;
            const int row = kd * KH + kh + mt / TPH;
            const int wp = (mt % TPH) * 16 + l15 + kw;
            abase[mi] = (row * WP + wp) * CINP + l4 * 8;
        }
        #pragma unroll
        for (int cp = 0; cp < CPT; ++cp) {
            const int chunk = tap * CPT + cp;
            short8v a[MW], b[NW];
            #pragma unroll
            for (int mi = 0; mi < MW; ++mi)
                a[mi] = *(const short8v*)&sh[abase[mi] + cp * 32];
            #pragma unroll
            for (int ni = 0; ni < NW; ++ni)
                b[ni] = bp[((size_t)(ng * NW + ni) * CHUNKS + chunk) * 64 + lane];
            #pragma unroll
            for (int mi = 0; mi < MW; ++mi)
                #pragma unroll
                for (int ni = 0; ni < NW; ++ni)
                    acc[mi][ni] = __builtin_amdgcn_mfma_f32_16x16x32_bf16(a[mi], b[ni], acc[mi][ni], 0, 0, 0);
        }
    }

    #pragma unroll
    for (int mi = 0; mi < MW; ++mi) {
        const int mt = mg * MW + mi;
        const int hout = h0 + mt / TPH;
        const int wbase = (mt % TPH) * 16 + l4 * 4;
        #pragma unroll
        for (int ni = 0; ni < NW; ++ni) {
            const int cout = (ng * NW + ni) * 16 + l15;
            const float bi = bias[cout];
            #pragma unroll
            for (int r = 0; r < 4; ++r) {
                const int w = wbase + r;
                if (w < W) {
                    float v = fmaxf(0.f, acc[mi][ni][r] + bi);
                    out[((((size_t)bn * DD + d) * H + hout) * W + w) * COUT + cout] = f2bf(v);
                }
            }
        }
    }
}

// ---------------------------------------------------------------------------
// MaxPool (1,2,2) valid, bf16 (unchanged).
// ---------------------------------------------------------------------------
template<int C, int HO, int WO>
__global__ __launch_bounds__(256)
void poolb_k(const unsigned short* __restrict__ in, unsigned short* __restrict__ out,
             int total8, size_t obase)
{
    constexpr int C8 = C / 8;
    for (int idx = blockIdx.x * 256 + threadIdx.x; idx < total8; idx += gridDim.x * 256) {
        int c8 = idx % C8;
        int t = idx / C8;
        int wo = t % WO; t /= WO;
        int ho = t % HO; t /= HO;            // t = nd
        size_t base = (((size_t)t * (2 * HO) + 2 * ho) * (2 * WO) + 2 * wo) * C + c8 * 8;
        short8v a = *(const short8v*)&in[base];
        short8v b = *(const short8v*)&in[base + C];
        short8v c = *(const short8v*)&in[base + (size_t)(2 * WO) * C];
        short8v e = *(const short8v*)&in[base + (size_t)(2 * WO) * C + C];
        unsigned short o[8];
        #pragma unroll
        for (int j = 0; j < 8; ++j) {
            unsigned short av = (unsigned short)a[j], bv = (unsigned short)b[j];
            unsigned short cv = (unsigned short)c[j], ev = (unsigned short)e[j];
            unsigned short m1 = av > bv ? av : bv;
            unsigned short m2 = cv > ev ? cv : ev;
            o[j] = m1 > m2 ? m1 : m2;
        }
        *(short8v*)&out[obase + (size_t)idx * 8] = *(short8v*)o;
    }
}

// ---------------------------------------------------------------------------
// GlobalAveragePooling3D (unchanged).
// ---------------------------------------------------------------------------
__global__ __launch_bounds__(1024)
void gapb_k(const unsigned short* __restrict__ in, float* __restrict__ outf)
{
    __shared__ float part[8][128];
    const int n = blockIdx.x;
    const int c = threadIdx.x;
    const int dy = threadIdx.y;
    float s = 0.f;
    const unsigned short* p = &in[((size_t)n * 1568 + dy * 196) * 128 + c];
    #pragma unroll 4
    for (int i = 0; i < 196; ++i) s += bf2f(p[(size_t)i * 128]);
    part[dy][c] = s;
    __syncthreads();
    if (dy == 0) {
        float t = 0.f;
        #pragma unroll
        for (int k = 0; k < 8; ++k) t += part[k][c];
        outf[n * 128 + c] = t * (1.f / 1568.f);
    }
}

// ---------------------------------------------------------------------------
// Layer-1 input projection (parallel, unchanged).
// ---------------------------------------------------------------------------
__global__ __launch_bounds__(192)
void xp1_k(const float* __restrict__ feats, const float* __restrict__ wx,
           const float* __restrict__ gb, float* __restrict__ xp1)
{
    __shared__ float xrow[128];
    const int tb = blockIdx.x;           // t*2 + b
    const int b = tb & 1, t = tb >> 1;
    const int j = threadIdx.x;
    if (j < 128) xrow[j] = feats[(b * 13 + t) * 128 + j];
    __syncthreads();
    float s = gb[j];
    #pragma unroll 16
    for (int k = 0; k < 128; ++k) s = fmaf(xrow[k], wx[k * 192 + j], s);
    xp1[tb * 192 + j] = s;
}

// ---------------------------------------------------------------------------
// GRU scan (3 layers) + head, single block 384.
// REVERTED to the round-14 verified version (88 us): the round-15 4-acc
// split REGRESSED to 139 us (defeated compiler load pipelining). Keep the
// single-accumulator loop; compiler hoists the independent LDS reads.
// ---------------------------------------------------------------------------
__global__ __launch_bounds__(384)
void gru2_k(const float* __restrict__ xp1,
            const float* __restrict__ g1_wh, const float* __restrict__ g1_b,
            const float* __restrict__ g2_wx, const float* __restrict__ g2_wh, const float* __restrict__ g2_b,
            const float* __restrict__ g3_wx, const float* __restrict__ g3_wh, const float* __restrict__ g3_b,
            const float* __restrict__ d1_w, const float* __restrict__ d1_b,
            const float* __restrict__ d2_w, const float* __restrict__ d2_b,
            const float* __restrict__ thr_w, const float* __restrict__ thr_b,
            const float* __restrict__ tori_w, const float* __restrict__ tori_b,
            float* __restrict__ out)
{
    __shared__ float xp[13 * 2 * 192];          // 19,968 B
    __shared__ float seq[26 * 64];              //  6,656 B
    __shared__ unsigned short wbuf[64 * 192];   // 24,576 B (bf16 weights)
    __shared__ float hbuf[2 * 64];
    __shared__ float rec[2 * 192];
    __shared__ float gbr[192];
    __shared__ float tmp[2 * 64];
    __shared__ float hd2[2 * 32];
    __shared__ float red[4];
    __shared__ float tl[4];
    const int tid = threadIdx.x;
    const int jj = tid % 192;
    const int bb = tid / 192;

    for (int i = tid; i < 13 * 2 * 192; i += 384) xp[i] = xp1[i];

    const float* WHs[3] = {g1_wh, g2_wh, g3_wh};
    const float* WXs[3] = {nullptr, g2_wx, g3_wx};
    const float* GBs[3] = {g1_b, g2_b, g3_b};

    for (int layer = 0; layer < 3; ++layer) {
        const float* gb = GBs[layer];
        if (layer > 0) {
            const float* wx = WXs[layer];
            for (int i = tid; i < 64 * 192; i += 384) wbuf[i] = f2bf(wx[i]);
            __syncthreads();
            const float bi = gb[jj];
            for (int t = 0; t < 13; ++t) {
                const float* xr = &seq[(bb * 13 + t) * 64];
                float s = bi;
                #pragma unroll 8
                for (int k = 0; k < 64; ++k) s = fmaf(xr[k], bf2f(wbuf[k * 192 + jj]), s);
                xp[(t * 2 + bb) * 192 + jj] = s;
            }
            __syncthreads();
        }
        const float* wh = WHs[layer];
        for (int i = tid; i < 64 * 192; i += 384) wbuf[i] = f2bf(wh[i]);
        if (tid < 192) gbr[tid] = gb[192 + tid];
        if (tid < 128) hbuf[tid] = 0.f;
        __syncthreads();
        for (int t = 0; t < 13; ++t) {
            {
                const float* hr = &hbuf[bb * 64];
                float s = gbr[jj];
                #pragma unroll 8
                for (int k = 0; k < 64; ++k) s = fmaf(hr[k], bf2f(wbuf[k * 192 + jj]), s);
                rec[tid] = s;
            }
            __syncthreads();
            if (tid < 128) {
                int b = tid / 64, u = tid % 64;
                const float* xpt = &xp[(t * 2 + b) * 192];
                const float* rc = &rec[b * 192];
                float z = sigmoidf(xpt[u] + rc[u]);
                float r = sigmoidf(xpt[64 + u] + rc[64 + u]);
                float hh = tanhf(xpt[128 + u] + r * rc[128 + u]);
                float hn = z * hbuf[b * 64 + u] + (1.f - z) * hh;
                hbuf[b * 64 + u] = hn;
                seq[(b * 13 + t) * 64 + u] = hn;
            }
            __syncthreads();
        }
    }

    if (tid < 128) {
        int b = tid / 64, u = tid % 64;
        float s = d1_b[u];
        for (int k = 0; k < 64; ++k) s = fmaf(hbuf[b * 64 + k], d1_w[k * 64 + u], s);
        tmp[b * 64 + u] = fmaxf(s, 0.f);
    }
    __syncthreads();
    if (tid < 64) {
        int b = tid / 32, u = tid % 32;
        float s = d2_b[u];
        for (int k = 0; k < 64; ++k) s = fmaf(tmp[b * 64 + k], d2_w[k * 32 + u], s);
        hd2[b * 32 + u] = fmaxf(s, 0.f);
    }
    __syncthreads();
    if (tid < 128) {
        int b = tid / 64, u = tid % 64;
        float s = thr_b[u];
        for (int k = 0; k < 32; ++k) s = fmaf(hd2[b * 32 + k], thr_w[k * 64 + u], s);
        tmp[b * 64 + u] = s;
    }
    if (tid >= 128 && tid < 132) {
        int i = tid - 128;
        int b = i >> 1, u = i & 1;
        float s = tori_b[u];
        for (int k = 0; k < 32; ++k) s = fmaf(hd2[b * 32 + k], tori_w[k * 2 + u], s);
        tl[i] = s;
    }
    __syncthreads();
    if (tid < 2) {
        float m = -1e30f;
        for (int u = 0; u < 64; ++u) m = fmaxf(m, tmp[tid * 64 + u]);
        float s = 0.f;
        for (int u = 0; u < 64; ++u) s += expf(tmp[tid * 64 + u] - m);
        red[tid * 2] = m;
        red[tid * 2 + 1] = s;
    }
    __syncthreads();
    if (tid < 128) {
        int b = tid >> 6;
        out[tid] = expf(tmp[tid] - red[b * 2]) / red[b * 2 + 1];
    }
    if (tid >= 128 && tid < 130) {
        int b = tid - 128;
        float a = tl[b * 2], c = tl[b * 2 + 1];
        float m = fmaxf(a, c);
        float e0 = expf(a - m), e1 = expf(c - m);
        float inv = 1.f / (e0 + e1);
        out[128 + b * 2 + 0] = e0 * inv;
        out[128 + b * 2 + 1] = e1 * inv;
    }
}

// ---------------------------------------------------------------------------
extern "C" void kernel_launch(void* const* d_in, const int* in_sizes, int n_in,
                              void* d_out, int out_size, void* d_ws, size_t ws_size,
                              hipStream_t stream) {
    const float* inputs = (const float*)d_in[0];
    const float* c11_k = (const float*)d_in[1];  const float* c11_b = (const float*)d_in[2];
    const float* c12_k = (const float*)d_in[3];  const float* c12_b = (const float*)d_in[4];
    const float* c21_k = (const float*)d_in[5];  const float* c21_b = (const float*)d_in[6];
    const float* c22_k = (const float*)d_in[7];  const float* c22_b = (const float*)d_in[8];
    const float* c31_k = (const float*)d_in[9];  const float* c31_b = (const float*)d_in[10];
    const float* c32_k = (const float*)d_in[11]; const float* c32_b = (const float*)d_in[12];
    const float* g1_wx = (const float*)d_in[13]; const float* g1_wh = (const float*)d_in[14]; const float* g1_b = (const float*)d_in[15];
    const float* g2_wx = (const float*)d_in[16]; const float* g2_wh = (const float*)d_in[17]; const float* g2_b = (const float*)d_in[18];
    const float* g3_wx = (const float*)d_in[19]; const float* g3_wh = (const float*)d_in[20]; const float* g3_b = (const float*)d_in[21];
    const float* d1_w = (const float*)d_in[22];  const float* d1_b = (const float*)d_in[23];
    const float* d2_w = (const float*)d_in[24];  const float* d2_b = (const float*)d_in[25];
    const float* thr_w = (const float*)d_in[26]; const float* thr_b = (const float*)d_in[27];
    const float* tori_w = (const float*)d_in[28]; const float* tori_b = (const float*)d_in[29];

    typedef unsigned short u16;
    char* base = (char*)d_ws;
    // packed weights, contiguous (bf16 elems): c12 @0, c21 @27648, c22 @82944,
    // c31 @193536, c32 @414720; end 857088 elems -> 1,714,176 B
    u16* pkall = (u16*)base;
    u16* pk12 = pkall;
    u16* pk21 = pkall + 27648;
    u16* pk22 = pkall + 82944;
    u16* pk31 = pkall + 193536;
    u16* pk32 = pkall + 414720;
    float* feats = (float*)(base + 1714176);   // 13,312 B
    float* xp1   = (float*)(base + 1727488);   // 19,968 B
    u16* p1 = (u16*)(base + 1747456);          // 10,436,608 B
    u16* hA = (u16*)(base + 12184064);         // 20,873,216 B
    u16* hB = (u16*)(base + 33057280);         // 20,873,216 B; total 53,930,496 B
    float* out = (float*)d_out;

    // pack all conv weights in one launch (graph-safe, recomputed every launch)
    pack_all_k<<<1674, 256, 0, stream>>>(c12_k, c21_k, c22_k, c31_k, c32_k, pkall);

    // stage 1 in two batch halves (keeps peak ws at 53.9 MB)
    for (int b = 0; b < 2; ++b) {
        conv_c11_k<<<13 * 8 * 14, dim3(64, 4), 0, stream>>>(inputs, c11_k, c11_b, hA, b);
        convmf_k<32, 32, 56, 56, 1, 2, 1><<<13 * 8 * 56, 256, 0, stream>>>(hA, pk12, c12_b, hB);
        poolb_k<32, 28, 28><<<1274, 256, 0, stream>>>(hB, p1, 13 * 8 * 28 * 28 * 4, (size_t)b * 2609152);
    }
    // stages 2-3 full batch (26 sequences)
    convmf_k<32, 64, 28, 28, 2, 2, 2><<<26 * 8 * 14, 256, 0, stream>>>(p1, pk21, c21_b, hA);
    convmf_k<64, 64, 28, 28, 1, 2, 1><<<26 * 8 * 28, 256, 0, stream>>>(hA, pk22, c22_b, hB);
    poolb_k<64, 14, 14><<<1274, 256, 0, stream>>>(hB, p1, 26 * 8 * 14 * 14 * 8, 0);
    convmf_k<64, 128, 14, 14, 2, 2, 2><<<26 * 8 * 7, 256, 0, stream>>>(p1, pk31, c31_b, hA);
    convmf_k<128, 128, 14, 14, 2, 2, 2><<<26 * 8 * 7, 256, 0, stream>>>(hA, pk32, c32_b, hB);
    gapb_k<<<26, dim3(128, 8), 0, stream>>>(hB, feats);

    // GRU: parallel layer-1 projection, then LDS-staged scan
    xp1_k<<<26, 192, 0, stream>>>(feats, g1_wx, g1_b, xp1);
    gru2_k<<<1, 384, 0, stream>>>(xp1,
        g1_wh, g1_b, g2_wx, g2_wh, g2_b, g3_wx, g3_wh, g3_b,
        d1_w, d1_b, d2_w, d2_b, thr_w, thr_b, tori_w, tori_b, out);
}